// Round 8
// baseline (457.899 us; speedup 1.0000x reference)
//
#include <hip/hip_runtime.h>
#include <math.h>

// ---------------------------------------------------------------- constants
#define BB 8
#define TT 2048
#define DV_ 1024
#define DA_ 128
#define D1_ 512
#define D2_ 128
#define DH_ 257
#define DHP 288            // padded (zeros): divisible by 32 for MFMA K-chunks
#define DG_ 128
#define MTOT (BB*TT)       // 16384 rows
#define NPX ((size_t)MTOT*DHP)

#define NEGS 0.01f
#define INV_E 0.36787944117144233f
#define CH 64              // scan chunk rows
#define HALO 64            // r^64 ~ 6e-11 rel: truncation ~2e-6 abs on px~3e4 —
                           // far below the reference's own fp32 rounding
#define UB 8               // scan batch: 8 rows of loads issued together

#define RS 40              // MLP1 LDS row stride (hw): 80 B -> 20-bank step/row
#define BKC 32             // MLP1 K-chunk (halfwords) — R3 best-measured config

// ---------------------------------------------------------------- workspace
static const size_t o_big = 0;                     // 16,777,216 f
static const size_t o_c1  = 16777216;              //  8,388,608 f
static const size_t o_c2  = o_c1 + 8388608;        //  2,097,152 f
static const size_t o_w   = o_c2 + 2097152;        //    663,552 f (split weights)
static const size_t o_S   = o_w + 663552;          //      2,304 f
static const size_t o_den = o_S + 2304;            //     16,384 f

// short offsets inside o_w
static const size_t sw_w1h = 0;          // 524,288
static const size_t sw_w1l = 524288;
static const size_t sw_w2h = 1048576;    // 65,536
static const size_t sw_w2l = 1114112;
static const size_t sw_g1h = 1179648;    // 36,864 ([128][288])
static const size_t sw_g1l = 1216512;
static const size_t sw_g2h = 1253376;
static const size_t sw_g2l = 1290240;

typedef __attribute__((ext_vector_type(8))) __bf16 bf16x8;
typedef __attribute__((ext_vector_type(8))) unsigned short us8;
typedef __attribute__((ext_vector_type(4))) float f32x4;

__device__ __forceinline__ float diag_w() {
    // identical fp32 ops to the generic path evaluated at xy == 1.0f
    float dd = logf(1.0f + sqrtf(1.0f*1.0f - 1.0f + 1e-7f));
    dd = fminf(fmaxf(dd, 1e-6f), 200.0f);
    float x2 = expf(-dd);
    return expf(x2) - 1.0f;
}

__device__ __forceinline__ unsigned short f2bf(float f) {
    unsigned int u = __float_as_uint(f);
    u += 0x7FFFu + ((u >> 16) & 1u);   // RNE
    return (unsigned short)(u >> 16);
}
__device__ __forceinline__ float bf2f(unsigned short h) {
    return __uint_as_float((unsigned int)h << 16);
}

// 8 fp32 -> split (hi,lo) bf16x8 — byte-identical math to the old k_split_in
__device__ __forceinline__ void cvt8(const float4 a, const float4 b,
                                     us8& h, us8& l) {
    unsigned short hh;
#define CV_(idx, val) hh = f2bf(val); h[idx] = hh; l[idx] = f2bf((val) - bf2f(hh));
    CV_(0, a.x) CV_(1, a.y) CV_(2, a.z) CV_(3, a.w)
    CV_(4, b.x) CV_(5, b.y) CV_(6, b.z) CV_(7, b.w)
#undef CV_
}

// ---------------------------------------------------------------- setup
// merged: den/S init + w1/w2 split + gw1/gw2 transpose-pad-split, one launch
// (was 3 dispatches). Block ranges: [0,64) init, [64,640) split_w,
// [640,928) padgw (2x144).
__global__ void k_setup(float* __restrict__ den, const int* __restrict__ seq,
                        float* __restrict__ S,
                        const float* __restrict__ w1, const float* __restrict__ w2,
                        unsigned short* __restrict__ h1, unsigned short* __restrict__ l1,
                        unsigned short* __restrict__ h2, unsigned short* __restrict__ l2,
                        const float* __restrict__ g1, const float* __restrict__ g2,
                        unsigned short* __restrict__ gh1, unsigned short* __restrict__ gl1,
                        unsigned short* __restrict__ gh2, unsigned short* __restrict__ gl2)
{
    const int bx = blockIdx.x;
    if (bx < 64) {
        int r = bx * 256 + threadIdx.x;   // 16384 total
        den[r] = (float)seq[r >> 11] + diag_w();
        if (r < BB * DHP) S[r] = 0.f;
    } else if (bx < 640) {
        size_t i = ((size_t)(bx - 64) * 256 + threadIdx.x) * 4;
        const float* src; unsigned short *h, *l; size_t o;
        if (i < (size_t)D1_ * DV_) { src = w1; h = h1; l = l1; o = i; }
        else {
            o = i - (size_t)D1_ * DV_;
            if (o >= (size_t)D2_ * D1_) return;
            src = w2; h = h2; l = l2;
        }
        float4 v = *(const float4*)(src + o);
        ushort4 hv, lv;
        hv.x = f2bf(v.x); lv.x = f2bf(v.x - bf2f(hv.x));
        hv.y = f2bf(v.y); lv.y = f2bf(v.y - bf2f(hv.y));
        hv.z = f2bf(v.z); lv.z = f2bf(v.z - bf2f(hv.z));
        hv.w = f2bf(v.w); lv.w = f2bf(v.w - bf2f(hv.w));
        *(ushort4*)(h + o) = hv;
        *(ushort4*)(l + o) = lv;
    } else {
        const int bb = bx - 640;          // 0..287
        const int zz = (bb >= 144);
        int i = (bb - (zz ? 144 : 0)) * 256 + threadIdx.x;   // DG*DHP = 36864
        if (i >= DG_ * DHP) return;
        const float* g = zz ? g2 : g1;
        unsigned short* th = zz ? gh2 : gh1;
        unsigned short* tl = zz ? gl2 : gl1;
        int c = i / DHP, k = i - c * DHP;
        float v = (k < DH_) ? g[k * DG_ + c] : 0.f;
        unsigned short hh = f2bf(v);
        th[i] = hh;
        tl[i] = f2bf(v - bf2f(hh));
    }
}

// ------------------------------------------------- MLP1: LDS-staged split GEMM
// R3-R7 ledger: all structural variants (waves/CU, blocks/CU, pipeline depth,
// phase count) land 95-105 us @ MfmaUtil ~20% — chunk-synchronous floor.
// This is the BEST-MEASURED variant (R3: 94.7-95.8 us): 512-thr blocks on a
// 128x128 tile (16 waves/CU), BKC=32, A fp32-direct + in-reg (hi,lo) split,
// B (L2-resident split W1) register double-buffered straight from global,
// LDS holds only A (40 KB). Bit-identical C1.
__global__ __launch_bounds__(512, 2) void gemm_mlp1(
    const float* __restrict__ inA,
    const unsigned short* __restrict__ Bh, const unsigned short* __restrict__ Bl,
    const float* __restrict__ bias,
    unsigned short* __restrict__ Ch, unsigned short* __restrict__ Cl)
{
    __shared__ unsigned short sm[2][2][128 * RS];   // [buf][Ah,Al] = 40 KB
    const int ib = blockIdx.x;               // 512 blocks
    const int x = ib & 7, slot = ib >> 3;    // xcd lane, 64 slots
    const int cc = slot & 3, g = slot >> 2;  // col-tile, panel group
    const int row0 = (x + 8 * g) * 128, col0 = cc * 128;
    const int tid = threadIdx.x;
    const int wave = tid >> 6, lane = tid & 63;
    const int r0w = (wave >> 2) * 64;                 // block-local row base
    const int c0 = col0 + (wave & 3) * 32;            // GLOBAL col base
    const int q = lane >> 4, m = lane & 15;
    // staging: thread covers row srow, 8-elem col slice
    const int srow = tid >> 2, scol = (tid & 3) << 3;
    const size_t gA0 = (size_t)(row0 + srow) * 1152 + scol;        // fp32 elems
    const int s0 = srow * RS + scol;
    // B fragment bases (global halfword offsets), static-indexed
    size_t bo_[2];
#pragma unroll
    for (int t = 0; t < 2; ++t) bo_[t] = (size_t)(c0 + t*16 + m) * DV_ + q*8;

    float4 a00, a01;
    bf16x8 fah[4], fal[4];
    bf16x8 bh0[2], bl0[2], bh1[2], bl1[2];

#define M1_LDGA(o) { \
    a00 = *(const float4*)(inA + gA0 + (o)); a01 = *(const float4*)(inA + gA0 + (o) + 4); }
#define M1_STAGE(BUF) { \
    us8 h_, l_; \
    cvt8(a00, a01, h_, l_); \
    *(us8*)&sm[BUF][0][s0] = h_; *(us8*)&sm[BUF][1][s0] = l_; }
#define M1_LDGB(S, o) \
    _Pragma("unroll") \
    for (int t = 0; t < 2; ++t) { \
        bh##S[t] = *(const bf16x8*)(Bh + bo_[t] + (o)); \
        bl##S[t] = *(const bf16x8*)(Bl + bo_[t] + (o)); }
#define M1_LOADA(BUF) \
    _Pragma("unroll") \
    for (int t = 0; t < 4; ++t) { \
        const int ra = (r0w + t*16 + m) * RS + q*8; \
        fah[t] = *(const bf16x8*)&sm[BUF][0][ra]; \
        fal[t] = *(const bf16x8*)&sm[BUF][1][ra]; }
#define M1_MFMA(S) \
    _Pragma("unroll") \
    for (int mi = 0; mi < 4; ++mi) \
        _Pragma("unroll") \
        for (int nj = 0; nj < 2; ++nj) { \
            acc[mi][nj] = __builtin_amdgcn_mfma_f32_16x16x32_bf16(fah[mi], bh##S[nj], acc[mi][nj], 0, 0, 0); \
            acc[mi][nj] = __builtin_amdgcn_mfma_f32_16x16x32_bf16(fal[mi], bh##S[nj], acc[mi][nj], 0, 0, 0); \
            acc[mi][nj] = __builtin_amdgcn_mfma_f32_16x16x32_bf16(fah[mi], bl##S[nj], acc[mi][nj], 0, 0, 0); \
        }

    f32x4 acc[4][2];
#pragma unroll
    for (int a = 0; a < 4; ++a)
#pragma unroll
        for (int c = 0; c < 2; ++c) acc[a][c] = (f32x4){0.f, 0.f, 0.f, 0.f};

    // prologue: chunk 0 -> sm[0], b0
    M1_LDGA(0)
    M1_STAGE(0)
    M1_LDGB(0, 0)
    __syncthreads();

    const int NI = (DV_ / BKC) / 2;   // 16 double-chunk iterations
    for (int i = 0; i < NI; ++i) {
        // even chunk 2i: A in sm[0], B in b0
        const size_t o1 = (size_t)(2*i + 1) * BKC;
        M1_LDGA(o1)          // prefetch A chunk 2i+1
        M1_LDGB(1, o1)       // prefetch B chunk 2i+1
        M1_LOADA(0)
        M1_MFMA(0)
        M1_STAGE(1)          // stage A chunk 2i+1
        __syncthreads();
        // odd chunk 2i+1: A in sm[1], B in b1
        if (i + 1 < NI) {
            const size_t o2 = (size_t)(2*i + 2) * BKC;
            M1_LDGA(o2)
            M1_LDGB(0, o2)
        }
        M1_LOADA(1)
        M1_MFMA(1)
        if (i + 1 < NI) { M1_STAGE(0) }
        __syncthreads();
    }
#undef M1_LDGA
#undef M1_STAGE
#undef M1_LDGB
#undef M1_LOADA
#undef M1_MFMA

    float bj[2];
#pragma unroll
    for (int nj = 0; nj < 2; ++nj) bj[nj] = bias[c0 + nj*16 + m];
#pragma unroll
    for (int mi = 0; mi < 4; ++mi)
#pragma unroll
        for (int nj = 0; nj < 2; ++nj)
#pragma unroll
            for (int t = 0; t < 4; ++t) {
                int i = row0 + r0w + mi*16 + q*4 + t;
                int j = c0 + nj*16 + m;
                float v = acc[mi][nj][t] + bj[nj];
                v = (v >= 0.f) ? v : NEGS * v;
                size_t o = (size_t)i * D1_ + j;
                unsigned short hh = f2bf(v);
                Ch[o] = hh;
                Cl[o] = f2bf(v - bf2f(hh));
            }
}

// ------------------------------------------------- split-bf16x3 MFMA cores
// 64-row-tile variant: 4 A frags, 2 B frags, stride LD (used by MLP2 + GC)
#define LOADK2(S, k0, LD) \
    _Pragma("unroll") \
    for (int t = 0; t < 4; ++t) { \
        size_t ao = (size_t)(r0 + t*16 + m) * (LD) + (k0) + q*8; \
        ah##S[t] = *(const bf16x8*)(Ah + ao); \
        al##S[t] = *(const bf16x8*)(Al + ao); \
    } \
    _Pragma("unroll") \
    for (int t = 0; t < 2; ++t) { \
        size_t bo = (size_t)(c0 + t*16 + m) * (LD) + (k0) + q*8; \
        bh##S[t] = *(const bf16x8*)(Bh + bo); \
        bl##S[t] = *(const bf16x8*)(Bl + bo); \
    }
#define MFMAK2(S) \
    _Pragma("unroll") \
    for (int mi = 0; mi < 4; ++mi) \
        _Pragma("unroll") \
        for (int nj = 0; nj < 2; ++nj) { \
            acc[mi][nj] = __builtin_amdgcn_mfma_f32_16x16x32_bf16(ah##S[mi], bh##S[nj], acc[mi][nj], 0, 0, 0); \
            acc[mi][nj] = __builtin_amdgcn_mfma_f32_16x16x32_bf16(al##S[mi], bh##S[nj], acc[mi][nj], 0, 0, 0); \
            acc[mi][nj] = __builtin_amdgcn_mfma_f32_16x16x32_bf16(ah##S[mi], bl##S[nj], acc[mi][nj], 0, 0, 0); \
        }

// MLP2: 64-row blocks x 128 cols, wave = 64x32 tile. 256 blocks.
// K-accumulation order identical to the old generic kernel -> bit-identical.
__global__ __launch_bounds__(256, 1) void gemm_mlp2(
    const unsigned short* __restrict__ Ah, const unsigned short* __restrict__ Al,
    const unsigned short* __restrict__ Bh, const unsigned short* __restrict__ Bl,
    const float* __restrict__ bias, float* __restrict__ Cf)
{
    const int row0 = blockIdx.x * 64;        // 256 blocks
    const int wave = threadIdx.x >> 6, lane = threadIdx.x & 63;
    const int r0 = row0, c0 = wave * 32;
    const int q = lane >> 4, m = lane & 15;
    f32x4 acc[4][2];
#pragma unroll
    for (int a = 0; a < 4; ++a)
#pragma unroll
        for (int c = 0; c < 2; ++c) acc[a][c] = (f32x4){0.f, 0.f, 0.f, 0.f};
    bf16x8 ah0[4], al0[4], bh0[2], bl0[2];
    bf16x8 ah1[4], al1[4], bh1[2], bl1[2];
    LOADK2(0, 0, D1_)
    for (int k0 = 0; k0 + 64 <= D1_; k0 += 64) {
        LOADK2(1, k0 + 32, D1_)
        MFMAK2(0)
        if (k0 + 64 < D1_) { LOADK2(0, k0 + 64, D1_) }
        MFMAK2(1)
    }
    float bj[2];
#pragma unroll
    for (int nj = 0; nj < 2; ++nj) bj[nj] = bias[c0 + nj*16 + m];
#pragma unroll
    for (int mi = 0; mi < 4; ++mi)
#pragma unroll
        for (int nj = 0; nj < 2; ++nj)
#pragma unroll
            for (int t = 0; t < 4; ++t) {
                int i = r0 + mi*16 + q*4 + t;
                int j = c0 + nj*16 + m;
                float v = acc[mi][nj][t] + bj[nj];
                v = (v >= 0.f) ? v : NEGS * v;
                Cf[(size_t)i * D2_ + j] = v;
            }
}

// ------------------------------------------------- merged graph-conv GEMMs
// z=0: x1 = leaky(y1 @ g1) with y1 FUSED — y1 elements are consumed exactly
// once here, so compute out=(S+accb+w*px)/den and split (hi,lo) in-register
// during fragment load (same fp32 expression + same split math as old k_y1 ->
// bit-identical). Eliminates the k_y1 dispatch and its ~57 MB of traffic.
// z=1: x2 = leaky(y2 @ g2), y2 from k_band (unchanged path).
// 64-row blocks; K-chunk order (0,32,..,256) + hh/lh/hl order unchanged.
__global__ __launch_bounds__(256, 1) void gemm_gc(
    const float* __restrict__ accb, const float* __restrict__ S,
    const float* __restrict__ den, const int* __restrict__ seq,
    const float* __restrict__ pxf,
    const unsigned short* __restrict__ A2h, const unsigned short* __restrict__ A2l,
    const unsigned short* __restrict__ G1h, const unsigned short* __restrict__ G1l,
    const unsigned short* __restrict__ G2h, const unsigned short* __restrict__ G2l,
    float* __restrict__ X1, float* __restrict__ X2)
{
    const int z = blockIdx.z;
    const int row0 = blockIdx.y * 64;        // 256 row-tiles x 2
    const int wave = threadIdx.x >> 6, lane = threadIdx.x & 63;
    const int r0 = row0, c0 = wave * 32;
    const int q = lane >> 4, m = lane & 15;
    f32x4 acc[4][2];
#pragma unroll
    for (int a = 0; a < 4; ++a)
#pragma unroll
        for (int c = 0; c < 2; ++c) acc[a][c] = (f32x4){0.f, 0.f, 0.f, 0.f};
    bf16x8 ah0[4], al0[4], bh0[2], bl0[2];
    bf16x8 ah1[4], al1[4], bh1[2], bl1[2];

    if (z == 0) {
        const unsigned short* Bh = G1h;
        const unsigned short* Bl = G1l;
        const int b = row0 >> 11;            // 64-row tile spans one batch
        const int nb = seq[b];
        const float* Sb = S + b * DHP;
        float dn[4]; bool vl[4];
#pragma unroll
        for (int t = 0; t < 4; ++t) {
            int rr = r0 + t*16 + m;
            vl[t] = (rr & (TT - 1)) < nb;
            dn[t] = den[rr];
        }
#define GLOADF(Sx, k0) \
    _Pragma("unroll") \
    for (int t = 0; t < 4; ++t) { \
        const int rr = r0 + t*16 + m; \
        const float* ap = accb + (size_t)rr * DHP + (k0) + q*8; \
        const float* pp = pxf  + (size_t)rr * DHP + (k0) + q*8; \
        const float* sp = Sb + (k0) + q*8; \
        us8 h_, l_; \
        _Pragma("unroll") \
        for (int e = 0; e < 8; ++e) { \
            float out = 0.f; \
            if (vl[t]) out = (sp[e] + ap[e] + diag_w() * pp[e]) / dn[t]; \
            unsigned short hh = f2bf(out); \
            h_[e] = hh; l_[e] = f2bf(out - bf2f(hh)); \
        } \
        ah##Sx[t] = *(bf16x8*)&h_; al##Sx[t] = *(bf16x8*)&l_; \
    } \
    _Pragma("unroll") \
    for (int t = 0; t < 2; ++t) { \
        size_t bo = (size_t)(c0 + t*16 + m) * DHP + (k0) + q*8; \
        bh##Sx[t] = *(const bf16x8*)(Bh + bo); \
        bl##Sx[t] = *(const bf16x8*)(Bl + bo); \
    }
        GLOADF(0, 0)
        int k0 = 0;
        for (; k0 + 64 <= DHP; k0 += 64) {
            GLOADF(1, k0 + 32)
            MFMAK2(0)
            if (k0 + 64 < DHP) { GLOADF(0, k0 + 64) }
            MFMAK2(1)
        }
        if (k0 < DHP) { MFMAK2(0) }   // K=288 tail (chunk 256)
#undef GLOADF
#pragma unroll
        for (int mi = 0; mi < 4; ++mi)
#pragma unroll
            for (int nj = 0; nj < 2; ++nj)
#pragma unroll
                for (int t = 0; t < 4; ++t) {
                    int i = r0 + mi*16 + q*4 + t;
                    int j = c0 + nj*16 + m;
                    float v = acc[mi][nj][t];
                    v = (v >= 0.f) ? v : NEGS * v;
                    X1[(size_t)i * DG_ + j] = v;
                }
    } else {
        const unsigned short* Ah = A2h;
        const unsigned short* Al = A2l;
        const unsigned short* Bh = G2h;
        const unsigned short* Bl = G2l;
        LOADK2(0, 0, DHP)
        int k0 = 0;
        for (; k0 + 64 <= DHP; k0 += 64) {
            LOADK2(1, k0 + 32, DHP)
            MFMAK2(0)
            if (k0 + 64 < DHP) { LOADK2(0, k0 + 64, DHP) }
            MFMAK2(1)
        }
        if (k0 < DHP) { MFMAK2(0) }   // K=288 tail (chunk 256)
#pragma unroll
        for (int mi = 0; mi < 4; ++mi)
#pragma unroll
            for (int nj = 0; nj < 2; ++nj)
#pragma unroll
                for (int t = 0; t < 4; ++t) {
                    int i = r0 + mi*16 + q*4 + t;
                    int j = c0 + nj*16 + m;
                    float v = acc[mi][nj][t];
                    v = (v >= 0.f) ? v : NEGS * v;
                    X2[(size_t)i * DG_ + j] = v;
                }
    }
}

// ------------------------------------------------- xy via bf16 MFMA (upper tri)
// Only observable effect: which pairs pass x2>0.8. Off-diag xy huge vs band
// [1,1.026]; bf16 error negligible -> classification identical to fp32/f64.
#define XLOAD(S, k0) \
    _Pragma("unroll") \
    for (int t = 0; t < 4; ++t) { \
        af##S[t] = *(const bf16x8*)(base + (size_t)(r0 + t*16 + m) * DHP + (k0) + q*8); \
        bf##S[t] = *(const bf16x8*)(base + (size_t)(c0 + t*16 + m) * DHP + (k0) + q*8); \
    }
#define XMFMA(S) \
    _Pragma("unroll") \
    for (int mi = 0; mi < 4; ++mi) \
        _Pragma("unroll") \
        for (int nj = 0; nj < 4; ++nj) \
            acc[mi][nj] = __builtin_amdgcn_mfma_f32_16x16x32_bf16(af##S[mi], bf##S[nj], acc[mi][nj], 0, 0, 0);

__global__ __launch_bounds__(256, 1) void k_xy_mfma(
    const unsigned short* __restrict__ pxb, const float* __restrict__ px,
    const int* __restrict__ seq, float* __restrict__ den, float* __restrict__ accb)
{
    const int b = blockIdx.z;
    const int bx = blockIdx.x, by = blockIdx.y;
    if (bx < by) return;
    const int nb = seq[b];
    const int row0 = by * 128, col0 = bx * 128;
    if (row0 >= nb || col0 >= nb) return;
    const int wave = threadIdx.x >> 6, lane = threadIdx.x & 63;
    const int r0 = row0 + (wave >> 1) * 64, c0 = col0 + (wave & 1) * 64;
    if (c0 + 63 < r0 || r0 >= nb || c0 >= nb) return;   // wave-uniform exits
    const unsigned short* base = pxb + (size_t)b * TT * DHP;
    const int q = lane >> 4, m = lane & 15;
    f32x4 acc[4][4];
#pragma unroll
    for (int a = 0; a < 4; ++a)
#pragma unroll
        for (int c = 0; c < 4; ++c) acc[a][c] = (f32x4){0.f, 0.f, 0.f, 0.f};
    bf16x8 af0[4], bf0[4], af1[4], bf1[4];
    XLOAD(0, 0)
    int k0 = 0;
    for (; k0 + 64 <= DHP; k0 += 64) {
        XLOAD(1, k0 + 32)
        XMFMA(0)
        if (k0 + 64 < DHP) { XLOAD(0, k0 + 64) }
        XMFMA(1)
    }
    if (k0 < DHP) { XMFMA(0) }
    const float* b32 = px + (size_t)b * TT * DHP;
    float cj[4], ci[4][4];
#pragma unroll
    for (int nj = 0; nj < 4; ++nj) cj[nj] = b32[(size_t)(c0 + nj*16 + m) * DHP];
#pragma unroll
    for (int mi = 0; mi < 4; ++mi)
#pragma unroll
        for (int t = 0; t < 4; ++t) ci[mi][t] = b32[(size_t)(r0 + mi*16 + q*4 + t) * DHP];
#pragma unroll
    for (int mi = 0; mi < 4; ++mi)
#pragma unroll
        for (int nj = 0; nj < 4; ++nj)
#pragma unroll
            for (int t = 0; t < 4; ++t) {
                int i = r0 + mi*16 + q*4 + t;
                int j = c0 + nj*16 + m;
                if (i < j && j < nb) {
                    float xyv = 2.f * ci[mi][t] * cj[nj] - acc[mi][nj][t];
                    float xym = fmaxf(xyv, 1.0f);
                    // xym >= 1.026 => x2 <= 0.798 < 0.8: no correction
                    if (xym < 1.026f) {
                        float dd = logf(xym + sqrtf(xym * xym - 1.0f + 1e-7f));
                        dd = fminf(fmaxf(dd, 1e-6f), 200.0f);
                        float x2v = expf(-dd);
                        if (x2v > 0.8f) {
                            float w = expf(x2v) - 1.0f;
                            atomicAdd(&den[b * TT + i], w);
                            atomicAdd(&den[b * TT + j], w);
                            const float* pi = b32 + (size_t)i * DHP;
                            const float* pj = b32 + (size_t)j * DHP;
                            float* ai = accb + ((size_t)(b * TT + i)) * DHP;
                            float* aj = accb + ((size_t)(b * TT + j)) * DHP;
                            for (int d = 0; d < DHP; ++d) {
                                atomicAdd(&ai[d], w * pj[d]);
                                atomicAdd(&aj[d], w * pi[d]);
                            }
                        }
                    }
                }
            }
}

// ------------------------------------------------- expmap0 (px fp32 + bf16)
// also zeroes this row's accb slice (accb overwrites C1, dead after MLP2).
__global__ __launch_bounds__(256) void k_proj(
    const float* __restrict__ C2, const float* __restrict__ inputs,
    float* __restrict__ px, unsigned short* __restrict__ pxb,
    float* __restrict__ accb)
{
    const int r = blockIdx.x;
    const int tid = threadIdx.x;
    float v = (tid < 128) ? C2[(size_t)r * 128 + tid]
                          : inputs[(size_t)r * 1152 + 1024 + (tid - 128)];
    float sq = v * v;
#pragma unroll
    for (int o = 32; o > 0; o >>= 1) sq += __shfl_down(sq, o, 64);
    __shared__ float wred[4];
    __shared__ float cs[2];
    if ((tid & 63) == 0) wred[tid >> 6] = sq;
    __syncthreads();
    if (tid == 0) {
        float n2 = fmaxf(wred[0] + wred[1] + wred[2] + wred[3], 1e-12f);
        float n = sqrtf(n2);
        cs[0] = coshf(n);
        cs[1] = sinhf(n) / n;
    }
    __syncthreads();
    float sv = cs[1] * v;
    px[(size_t)r * DHP + 1 + tid] = sv;
    pxb[(size_t)r * DHP + 1 + tid] = f2bf(sv);
    if (tid == 0) {
        px[(size_t)r * DHP] = cs[0];
        pxb[(size_t)r * DHP] = f2bf(cs[0]);
    }
    if (tid < DHP - DH_) {   // 31 pad zeros
        px[(size_t)r * DHP + DH_ + tid] = 0.f;
        pxb[(size_t)r * DHP + DH_ + tid] = 0;
    }
    float* ab = accb + (size_t)r * DHP;
    ab[tid] = 0.f;
    if (tid < DHP - 256) ab[256 + tid] = 0.f;
}

// ------------------------------------------------- per-batch valid column sum
__global__ __launch_bounds__(256) void k_ssum(
    const float* __restrict__ px, const int* __restrict__ seq,
    float* __restrict__ S)
{
    const int b = blockIdx.x, chunk = blockIdx.y, tid = threadIdx.x;
    const int nb = seq[b];
    const int j0 = chunk * 32;
    const int j1 = (j0 + 32 < nb) ? j0 + 32 : nb;
    float a0 = 0.f, a1 = 0.f;
    const bool hasB = (tid < DHP - 256);
    for (int j = j0; j < j1; ++j) {
        const float* row = px + ((size_t)(b * TT + j)) * DHP;
        a0 += row[tid];
        if (hasB) a1 += row[256 + tid];
    }
    if (j1 > j0) {
        atomicAdd(&S[b * DHP + tid], a0);
        if (hasB) atomicAdd(&S[b * DHP + 256 + tid], a1);
    }
}

// ------------------------------------------------- disadj @ px via dual scan
// disadj[i,j] = r^|i-j|: full matvec = fwd + bwd first-order recursions.
__global__ __launch_bounds__(256) void k_band(
    const float* __restrict__ px,
    unsigned short* __restrict__ yh, unsigned short* __restrict__ yl)
{
    __shared__ float Fs[CH][DHP];   // 73,728 B
    const int b = blockIdx.y;
    const int i0 = blockIdx.x * CH;
    const int tid = threadIdx.x;
    const bool hasB = (tid < DHP - 256);
    const float r = expf(-INV_E);
    const float* base = px + (size_t)b * TT * DHP;

    // forward scan with left halo (batched)
    {
        const int jlo = (i0 - HALO > 0) ? i0 - HALO : 0;   // length mult of UB
        float LA = 0.f, LB = 0.f;
        for (int j = jlo; j < i0 + CH; j += UB) {
            float va[UB], vb[UB];
#pragma unroll
            for (int u = 0; u < UB; ++u) {
                const float* row = base + (size_t)(j + u) * DHP;
                va[u] = row[tid];
                vb[u] = hasB ? row[256 + tid] : 0.f;
            }
#pragma unroll
            for (int u = 0; u < UB; ++u) {
                LA = fmaf(r, LA, va[u]);
                LB = fmaf(r, LB, vb[u]);
                const int jj = j + u;
                if (jj >= i0) {
                    Fs[jj - i0][tid] = LA;
                    if (hasB) Fs[jj - i0][256 + tid] = LB;
                }
            }
        }
    }
    __syncthreads();
    // backward: halo warmup (batched), then chunk phase with emit
    {
        const int jhi = (i0 + CH - 1 + HALO < TT - 1) ? i0 + CH - 1 + HALO : TT - 1;
        float RA = 0.f, RB = 0.f;
        int j = jhi;
        for (; j >= i0 + CH; j -= UB) {    // warmup length mult of UB
            float va[UB], vb[UB];
#pragma unroll
            for (int u = 0; u < UB; ++u) {
                const float* row = base + (size_t)(j - u) * DHP;
                va[u] = row[tid];
                vb[u] = hasB ? row[256 + tid] : 0.f;
            }
#pragma unroll
            for (int u = 0; u < UB; ++u) {
                RA = fmaf(r, RA, va[u]);
                RB = fmaf(r, RB, vb[u]);
            }
        }
        for (; j >= i0; j -= UB) {         // chunk phase: emit every row
            float va[UB], vb[UB];
#pragma unroll
            for (int u = 0; u < UB; ++u) {
                const float* row = base + (size_t)(j - u) * DHP;
                va[u] = row[tid];
                vb[u] = hasB ? row[256 + tid] : 0.f;
            }
#pragma unroll
            for (int u = 0; u < UB; ++u) {
                const int jj = j - u;
                RA = fmaf(r, RA, va[u]);
                RB = fmaf(r, RB, vb[u]);
                size_t o = ((size_t)(b * TT + jj)) * DHP + tid;
                float ya = Fs[jj - i0][tid] + RA - va[u];
                unsigned short hh = f2bf(ya);
                yh[o] = hh; yl[o] = f2bf(ya - bf2f(hh));
                if (hasB) {
                    float yb = Fs[jj - i0][256 + tid] + RB - vb[u];
                    size_t ob = o + 256;
                    unsigned short h2 = f2bf(yb);
                    yh[ob] = h2; yl[ob] = f2bf(yb - bf2f(h2));
                }
            }
        }
    }
}

// ------------------------------------------------- frame_prob
__global__ __launch_bounds__(256) void k_frame(
    const float* __restrict__ x1, const float* __restrict__ x2f,
    const float* __restrict__ cls_w, const float* __restrict__ cls_b,
    float* __restrict__ dout)
{
    const int r = blockIdx.x * 4 + (threadIdx.x >> 6);
    const int lane = threadIdx.x & 63;
    float s = 0.f;
#pragma unroll
    for (int t = 0; t < 2; ++t) {
        int g = lane + t * 64;
        float cw1 = cls_w[g];
        if (g == 0) cw1 = -cw1;      // signs: only dim 0 negated
        s += x1[(size_t)r * DG_ + g] * cw1;
        s += x2f[(size_t)r * DG_ + g] * cls_w[DG_ + g];
    }
#pragma unroll
    for (int o = 32; o > 0; o >>= 1) s += __shfl_down(s, o, 64);
    if (lane == 0) dout[8 + r] = 2.0f + 2.0f * s + cls_b[0];
}

// ------------------------------------------------- top-k MIL (bitonic sort)
__global__ __launch_bounds__(1024) void k_clas(
    const int* __restrict__ seq, float* __restrict__ dout)
{
    __shared__ float s[TT];
    const int b = blockIdx.x, tid = threadIdx.x;
    const int nb = seq[b];
    for (int t = tid; t < TT; t += 1024)
        s[t] = (t < nb) ? dout[8 + b * TT + t] : -1e30f;
    __syncthreads();
    for (int k = 2; k <= TT; k <<= 1)
        for (int j = k >> 1; j > 0; j >>= 1) {
            for (int i = tid; i < TT; i += 1024) {
                int ixj = i ^ j;
                if (ixj > i) {
                    float a = s[i], c = s[ixj];
                    bool descBlk = ((i & k) == 0);
                    if (descBlk ? (a < c) : (a > c)) { s[i] = c; s[ixj] = a; }
                }
            }
            __syncthreads();
        }
    const int kk = nb / 16 + 1;
    float part = 0.f;
    for (int t = tid; t < kk; t += 1024) part += s[t];
#pragma unroll
    for (int o = 32; o > 0; o >>= 1) part += __shfl_down(part, o, 64);
    __shared__ float wred[16];
    if ((tid & 63) == 0) wred[tid >> 6] = part;
    __syncthreads();
    if (tid == 0) {
        float mil = 0.f;
#pragma unroll
        for (int t = 0; t < 16; ++t) mil += wred[t];
        mil /= (float)kk;
        dout[b] = 1.f / (1.f + expf(-mil));
    }
}

// ---------------------------------------------------------------- launch
extern "C" void kernel_launch(void* const* d_in, const int* in_sizes, int n_in,
                              void* d_out, int out_size, void* d_ws, size_t ws_size,
                              hipStream_t stream) {
    (void)in_sizes; (void)n_in; (void)out_size; (void)ws_size;
    const float* inputs = (const float*)d_in[0];
    const int*   seq    = (const int*)d_in[1];
    const float* w1     = (const float*)d_in[2];
    const float* b1     = (const float*)d_in[3];
    const float* w2     = (const float*)d_in[4];
    const float* b2     = (const float*)d_in[5];
    const float* gw1    = (const float*)d_in[6];
    const float* gw2    = (const float*)d_in[7];
    const float* cls_w  = (const float*)d_in[8];
    const float* cls_b  = (const float*)d_in[9];
    float* dout = (float*)d_out;
    float* ws = (float*)d_ws;

    // o_big region: px + pxb + y2 (y1 no longer materialized)
    float* px  = ws + o_big;
    unsigned short* pxb = (unsigned short*)(ws + o_big + 4718592);
    unsigned short* y2h = (unsigned short*)(ws + o_big + 7077888);
    unsigned short* y2l = y2h + NPX;
    // o_c1 region: C1h/C1l -> accb + x1
    unsigned short* C1h = (unsigned short*)(ws + o_c1);
    unsigned short* C1l = C1h + (size_t)MTOT * D1_;
    float* accb = ws + o_c1;
    float* x1   = ws + o_c1 + 4718592;
    // o_c2 region: C2 -> x2f
    float* C2  = ws + o_c2;
    float* x2f = ws + o_c2;
    // weights
    unsigned short* wsS = (unsigned short*)(ws + o_w);
    unsigned short *W1h = wsS + sw_w1h, *W1l = wsS + sw_w1l;
    unsigned short *W2h = wsS + sw_w2h, *W2l = wsS + sw_w2l;
    unsigned short *g1h = wsS + sw_g1h, *g1l = wsS + sw_g1l;
    unsigned short *g2h = wsS + sw_g2h, *g2l = wsS + sw_g2l;
    float* S   = ws + o_S;
    float* den = ws + o_den;

    // merged init + weight splits (1 dispatch, was 3)
    k_setup<<<928, 256, 0, stream>>>(den, seq, S, w1, w2, W1h, W1l, W2h, W2l,
                                     gw1, gw2, g1h, g1l, g2h, g2l);

    // MLP1: R3 best-measured config (512-thr, 128x128, BKC=32, B direct)
    gemm_mlp1<<<512, 512, 0, stream>>>(inputs, W1h, W1l, b1, C1h, C1l);
    // MLP2: 64-row tiles -> 256 blocks
    gemm_mlp2<<<256, 256, 0, stream>>>(C1h, C1l, W2h, W2l, b2, C2);

    // expmap0 (px/pxb overwrite o_big) + accb zeroing (C1 dead after MLP2)
    k_proj<<<MTOT, 256, 0, stream>>>(C2, inputs, px, pxb, accb);

    // valid column sums
    k_ssum<<<dim3(BB, TT / 32), 256, 0, stream>>>(px, seq, S);

    // Lorentz similarity via bf16 MFMA, upper triangle
    k_xy_mfma<<<dim3(TT / 128, TT / 128, BB), 256, 0, stream>>>(pxb, px, seq, den, accb);

    // disadj @ px via batched dual scan -> split bf16 y2
    k_band<<<dim3(TT / CH, BB), 256, 0, stream>>>(px, y2h, y2l);

    // graph-conv projections: z=0 fuses y1 computation (k_y1 eliminated)
    gemm_gc<<<dim3(1, MTOT / 64, 2), 256, 0, stream>>>(
        accb, S, den, seq, px, y2h, y2l, g1h, g1l, g2h, g2l, x1, x2f);

    // frame_prob + MIL
    k_frame<<<MTOT / 4, 256, 0, stream>>>(x1, x2f, cls_w, cls_b, dout);
    k_clas<<<BB, 1024, 0, stream>>>(seq, dout);
}

// Round 9
// 395.389 us; speedup vs baseline: 1.1581x; 1.1581x over previous
//
#include <hip/hip_runtime.h>
#include <math.h>

// ---------------------------------------------------------------- constants
#define BB 8
#define TT 2048
#define DV_ 1024
#define DA_ 128
#define D1_ 512
#define D2_ 128
#define DH_ 257
#define DHP 288            // padded (zeros): divisible by 32 for MFMA K-chunks
#define DG_ 128
#define MTOT (BB*TT)       // 16384 rows
#define NPX ((size_t)MTOT*DHP)

#define NEGS 0.01f
#define INV_E 0.36787944117144233f
#define CH 64              // scan chunk rows
#define HALO 64            // r^64 ~ 6e-11 rel: truncation ~2e-6 abs on px~3e4 —
                           // far below the reference's own fp32 rounding
#define UB 8               // scan batch: 8 rows of loads issued together

#define RS 40              // MLP1 LDS row stride (hw): 80 B -> 20-bank step/row
#define BKC 32             // MLP1 K-chunk (halfwords) — R3 best-measured config

// ---------------------------------------------------------------- workspace
static const size_t o_big = 0;                     // 16,777,216 f
static const size_t o_c1  = 16777216;              //  8,388,608 f
static const size_t o_c2  = o_c1 + 8388608;        //  2,097,152 f
static const size_t o_w   = o_c2 + 2097152;        //    663,552 f (split weights)
static const size_t o_S   = o_w + 663552;          //      2,304 f
static const size_t o_den = o_S + 2304;            //     16,384 f

// short offsets inside o_w
static const size_t sw_w1h = 0;          // 524,288
static const size_t sw_w1l = 524288;
static const size_t sw_w2h = 1048576;    // 65,536
static const size_t sw_w2l = 1114112;
static const size_t sw_g1h = 1179648;    // 36,864 ([128][288])
static const size_t sw_g1l = 1216512;
static const size_t sw_g2h = 1253376;
static const size_t sw_g2l = 1290240;

typedef __attribute__((ext_vector_type(8))) __bf16 bf16x8;
typedef __attribute__((ext_vector_type(8))) unsigned short us8;
typedef __attribute__((ext_vector_type(4))) float f32x4;

__device__ __forceinline__ float diag_w() {
    // identical fp32 ops to the generic path evaluated at xy == 1.0f
    float dd = logf(1.0f + sqrtf(1.0f*1.0f - 1.0f + 1e-7f));
    dd = fminf(fmaxf(dd, 1e-6f), 200.0f);
    float x2 = expf(-dd);
    return expf(x2) - 1.0f;
}

__device__ __forceinline__ unsigned short f2bf(float f) {
    unsigned int u = __float_as_uint(f);
    u += 0x7FFFu + ((u >> 16) & 1u);   // RNE
    return (unsigned short)(u >> 16);
}
__device__ __forceinline__ float bf2f(unsigned short h) {
    return __uint_as_float((unsigned int)h << 16);
}

// 8 fp32 -> split (hi,lo) bf16x8 — byte-identical math to the old k_split_in
__device__ __forceinline__ void cvt8(const float4 a, const float4 b,
                                     us8& h, us8& l) {
    unsigned short hh;
#define CV_(idx, val) hh = f2bf(val); h[idx] = hh; l[idx] = f2bf((val) - bf2f(hh));
    CV_(0, a.x) CV_(1, a.y) CV_(2, a.z) CV_(3, a.w)
    CV_(4, b.x) CV_(5, b.y) CV_(6, b.z) CV_(7, b.w)
#undef CV_
}

// ---------------------------------------------------------------- setup
// merged: den/S init + w1/w2 split + gw1/gw2 transpose-pad-split, one launch
// (was 3 dispatches). Block ranges: [0,64) init, [64,640) split_w,
// [640,928) padgw (2x144).
__global__ void k_setup(float* __restrict__ den, const int* __restrict__ seq,
                        float* __restrict__ S,
                        const float* __restrict__ w1, const float* __restrict__ w2,
                        unsigned short* __restrict__ h1, unsigned short* __restrict__ l1,
                        unsigned short* __restrict__ h2, unsigned short* __restrict__ l2,
                        const float* __restrict__ g1, const float* __restrict__ g2,
                        unsigned short* __restrict__ gh1, unsigned short* __restrict__ gl1,
                        unsigned short* __restrict__ gh2, unsigned short* __restrict__ gl2)
{
    const int bx = blockIdx.x;
    if (bx < 64) {
        int r = bx * 256 + threadIdx.x;   // 16384 total
        den[r] = (float)seq[r >> 11] + diag_w();
        if (r < BB * DHP) S[r] = 0.f;
    } else if (bx < 640) {
        size_t i = ((size_t)(bx - 64) * 256 + threadIdx.x) * 4;
        const float* src; unsigned short *h, *l; size_t o;
        if (i < (size_t)D1_ * DV_) { src = w1; h = h1; l = l1; o = i; }
        else {
            o = i - (size_t)D1_ * DV_;
            if (o >= (size_t)D2_ * D1_) return;
            src = w2; h = h2; l = l2;
        }
        float4 v = *(const float4*)(src + o);
        ushort4 hv, lv;
        hv.x = f2bf(v.x); lv.x = f2bf(v.x - bf2f(hv.x));
        hv.y = f2bf(v.y); lv.y = f2bf(v.y - bf2f(hv.y));
        hv.z = f2bf(v.z); lv.z = f2bf(v.z - bf2f(hv.z));
        hv.w = f2bf(v.w); lv.w = f2bf(v.w - bf2f(hv.w));
        *(ushort4*)(h + o) = hv;
        *(ushort4*)(l + o) = lv;
    } else {
        const int bb = bx - 640;          // 0..287
        const int zz = (bb >= 144);
        int i = (bb - (zz ? 144 : 0)) * 256 + threadIdx.x;   // DG*DHP = 36864
        if (i >= DG_ * DHP) return;
        const float* g = zz ? g2 : g1;
        unsigned short* th = zz ? gh2 : gh1;
        unsigned short* tl = zz ? gl2 : gl1;
        int c = i / DHP, k = i - c * DHP;
        float v = (k < DH_) ? g[k * DG_ + c] : 0.f;
        unsigned short hh = f2bf(v);
        th[i] = hh;
        tl[i] = f2bf(v - bf2f(hh));
    }
}

// ------------------------------------------------- MLP1: LDS-staged split GEMM
// R3-R7 ledger: all structural variants (waves/CU, blocks/CU, pipeline depth,
// phase count) land 95-105 us @ MfmaUtil ~20% — chunk-synchronous floor.
// BEST-MEASURED variant (R3/R8: 95-98 us): 512-thr blocks on a 128x128 tile
// (16 waves/CU), BKC=32, A fp32-direct + in-reg (hi,lo) split, B (L2-resident
// split W1) register double-buffered straight from global, LDS holds only A.
__global__ __launch_bounds__(512, 2) void gemm_mlp1(
    const float* __restrict__ inA,
    const unsigned short* __restrict__ Bh, const unsigned short* __restrict__ Bl,
    const float* __restrict__ bias,
    unsigned short* __restrict__ Ch, unsigned short* __restrict__ Cl)
{
    __shared__ unsigned short sm[2][2][128 * RS];   // [buf][Ah,Al] = 40 KB
    const int ib = blockIdx.x;               // 512 blocks
    const int x = ib & 7, slot = ib >> 3;    // xcd lane, 64 slots
    const int cc = slot & 3, g = slot >> 2;  // col-tile, panel group
    const int row0 = (x + 8 * g) * 128, col0 = cc * 128;
    const int tid = threadIdx.x;
    const int wave = tid >> 6, lane = tid & 63;
    const int r0w = (wave >> 2) * 64;                 // block-local row base
    const int c0 = col0 + (wave & 3) * 32;            // GLOBAL col base
    const int q = lane >> 4, m = lane & 15;
    // staging: thread covers row srow, 8-elem col slice
    const int srow = tid >> 2, scol = (tid & 3) << 3;
    const size_t gA0 = (size_t)(row0 + srow) * 1152 + scol;        // fp32 elems
    const int s0 = srow * RS + scol;
    // B fragment bases (global halfword offsets), static-indexed
    size_t bo_[2];
#pragma unroll
    for (int t = 0; t < 2; ++t) bo_[t] = (size_t)(c0 + t*16 + m) * DV_ + q*8;

    float4 a00, a01;
    bf16x8 fah[4], fal[4];
    bf16x8 bh0[2], bl0[2], bh1[2], bl1[2];

#define M1_LDGA(o) { \
    a00 = *(const float4*)(inA + gA0 + (o)); a01 = *(const float4*)(inA + gA0 + (o) + 4); }
#define M1_STAGE(BUF) { \
    us8 h_, l_; \
    cvt8(a00, a01, h_, l_); \
    *(us8*)&sm[BUF][0][s0] = h_; *(us8*)&sm[BUF][1][s0] = l_; }
#define M1_LDGB(S, o) \
    _Pragma("unroll") \
    for (int t = 0; t < 2; ++t) { \
        bh##S[t] = *(const bf16x8*)(Bh + bo_[t] + (o)); \
        bl##S[t] = *(const bf16x8*)(Bl + bo_[t] + (o)); }
#define M1_LOADA(BUF) \
    _Pragma("unroll") \
    for (int t = 0; t < 4; ++t) { \
        const int ra = (r0w + t*16 + m) * RS + q*8; \
        fah[t] = *(const bf16x8*)&sm[BUF][0][ra]; \
        fal[t] = *(const bf16x8*)&sm[BUF][1][ra]; }
#define M1_MFMA(S) \
    _Pragma("unroll") \
    for (int mi = 0; mi < 4; ++mi) \
        _Pragma("unroll") \
        for (int nj = 0; nj < 2; ++nj) { \
            acc[mi][nj] = __builtin_amdgcn_mfma_f32_16x16x32_bf16(fah[mi], bh##S[nj], acc[mi][nj], 0, 0, 0); \
            acc[mi][nj] = __builtin_amdgcn_mfma_f32_16x16x32_bf16(fal[mi], bh##S[nj], acc[mi][nj], 0, 0, 0); \
            acc[mi][nj] = __builtin_amdgcn_mfma_f32_16x16x32_bf16(fah[mi], bl##S[nj], acc[mi][nj], 0, 0, 0); \
        }

    f32x4 acc[4][2];
#pragma unroll
    for (int a = 0; a < 4; ++a)
#pragma unroll
        for (int c = 0; c < 2; ++c) acc[a][c] = (f32x4){0.f, 0.f, 0.f, 0.f};

    // prologue: chunk 0 -> sm[0], b0
    M1_LDGA(0)
    M1_STAGE(0)
    M1_LDGB(0, 0)
    __syncthreads();

    const int NI = (DV_ / BKC) / 2;   // 16 double-chunk iterations
    for (int i = 0; i < NI; ++i) {
        // even chunk 2i: A in sm[0], B in b0
        const size_t o1 = (size_t)(2*i + 1) * BKC;
        M1_LDGA(o1)          // prefetch A chunk 2i+1
        M1_LDGB(1, o1)       // prefetch B chunk 2i+1
        M1_LOADA(0)
        M1_MFMA(0)
        M1_STAGE(1)          // stage A chunk 2i+1
        __syncthreads();
        // odd chunk 2i+1: A in sm[1], B in b1
        if (i + 1 < NI) {
            const size_t o2 = (size_t)(2*i + 2) * BKC;
            M1_LDGA(o2)
            M1_LDGB(0, o2)
        }
        M1_LOADA(1)
        M1_MFMA(1)
        if (i + 1 < NI) { M1_STAGE(0) }
        __syncthreads();
    }
#undef M1_LDGA
#undef M1_STAGE
#undef M1_LDGB
#undef M1_LOADA
#undef M1_MFMA

    float bj[2];
#pragma unroll
    for (int nj = 0; nj < 2; ++nj) bj[nj] = bias[c0 + nj*16 + m];
#pragma unroll
    for (int mi = 0; mi < 4; ++mi)
#pragma unroll
        for (int nj = 0; nj < 2; ++nj)
#pragma unroll
            for (int t = 0; t < 4; ++t) {
                int i = row0 + r0w + mi*16 + q*4 + t;
                int j = c0 + nj*16 + m;
                float v = acc[mi][nj][t] + bj[nj];
                v = (v >= 0.f) ? v : NEGS * v;
                size_t o = (size_t)i * D1_ + j;
                unsigned short hh = f2bf(v);
                Ch[o] = hh;
                Cl[o] = f2bf(v - bf2f(hh));
            }
}

// ------------------------------------------------- split-bf16x3 MFMA cores
// 128-row-tile core: 4 A frags, 4 B frags (used by gemm_gc — best-measured)
#define LOADK(S, k0) \
    _Pragma("unroll") \
    for (int t = 0; t < 4; ++t) { \
        size_t ao = (size_t)(r0 + t*16 + m) * lda + (k0) + q*8; \
        size_t bo = (size_t)(c0 + t*16 + m) * ldb + (k0) + q*8; \
        ah##S[t] = *(const bf16x8*)(Ah + ao); \
        al##S[t] = *(const bf16x8*)(Al + ao); \
        bh##S[t] = *(const bf16x8*)(Bh + bo); \
        bl##S[t] = *(const bf16x8*)(Bl + bo); \
    }
#define MFMAK(S) \
    _Pragma("unroll") \
    for (int mi = 0; mi < 4; ++mi) \
        _Pragma("unroll") \
        for (int nj = 0; nj < 4; ++nj) { \
            acc[mi][nj] = __builtin_amdgcn_mfma_f32_16x16x32_bf16(ah##S[mi], bh##S[nj], acc[mi][nj], 0, 0, 0); \
            acc[mi][nj] = __builtin_amdgcn_mfma_f32_16x16x32_bf16(al##S[mi], bh##S[nj], acc[mi][nj], 0, 0, 0); \
            acc[mi][nj] = __builtin_amdgcn_mfma_f32_16x16x32_bf16(ah##S[mi], bl##S[nj], acc[mi][nj], 0, 0, 0); \
        }

// 64-row-tile core: 4 A frags, 2 B frags, stride LD (used by MLP2)
#define LOADK2(S, k0, LD) \
    _Pragma("unroll") \
    for (int t = 0; t < 4; ++t) { \
        size_t ao = (size_t)(r0 + t*16 + m) * (LD) + (k0) + q*8; \
        ah##S[t] = *(const bf16x8*)(Ah + ao); \
        al##S[t] = *(const bf16x8*)(Al + ao); \
    } \
    _Pragma("unroll") \
    for (int t = 0; t < 2; ++t) { \
        size_t bo = (size_t)(c0 + t*16 + m) * (LD) + (k0) + q*8; \
        bh##S[t] = *(const bf16x8*)(Bh + bo); \
        bl##S[t] = *(const bf16x8*)(Bl + bo); \
    }
#define MFMAK2(S) \
    _Pragma("unroll") \
    for (int mi = 0; mi < 4; ++mi) \
        _Pragma("unroll") \
        for (int nj = 0; nj < 2; ++nj) { \
            acc[mi][nj] = __builtin_amdgcn_mfma_f32_16x16x32_bf16(ah##S[mi], bh##S[nj], acc[mi][nj], 0, 0, 0); \
            acc[mi][nj] = __builtin_amdgcn_mfma_f32_16x16x32_bf16(al##S[mi], bh##S[nj], acc[mi][nj], 0, 0, 0); \
            acc[mi][nj] = __builtin_amdgcn_mfma_f32_16x16x32_bf16(ah##S[mi], bl##S[nj], acc[mi][nj], 0, 0, 0); \
        }

// MLP2: 64-row blocks x 128 cols, wave = 64x32 tile. 256 blocks.
__global__ __launch_bounds__(256, 1) void gemm_mlp2(
    const unsigned short* __restrict__ Ah, const unsigned short* __restrict__ Al,
    const unsigned short* __restrict__ Bh, const unsigned short* __restrict__ Bl,
    const float* __restrict__ bias, float* __restrict__ Cf)
{
    const int row0 = blockIdx.x * 64;        // 256 blocks
    const int wave = threadIdx.x >> 6, lane = threadIdx.x & 63;
    const int r0 = row0, c0 = wave * 32;
    const int q = lane >> 4, m = lane & 15;
    f32x4 acc[4][2];
#pragma unroll
    for (int a = 0; a < 4; ++a)
#pragma unroll
        for (int c = 0; c < 2; ++c) acc[a][c] = (f32x4){0.f, 0.f, 0.f, 0.f};
    bf16x8 ah0[4], al0[4], bh0[2], bl0[2];
    bf16x8 ah1[4], al1[4], bh1[2], bl1[2];
    LOADK2(0, 0, D1_)
    for (int k0 = 0; k0 + 64 <= D1_; k0 += 64) {
        LOADK2(1, k0 + 32, D1_)
        MFMAK2(0)
        if (k0 + 64 < D1_) { LOADK2(0, k0 + 64, D1_) }
        MFMAK2(1)
    }
    float bj[2];
#pragma unroll
    for (int nj = 0; nj < 2; ++nj) bj[nj] = bias[c0 + nj*16 + m];
#pragma unroll
    for (int mi = 0; mi < 4; ++mi)
#pragma unroll
        for (int nj = 0; nj < 2; ++nj)
#pragma unroll
            for (int t = 0; t < 4; ++t) {
                int i = r0 + mi*16 + q*4 + t;
                int j = c0 + nj*16 + m;
                float v = acc[mi][nj][t] + bj[nj];
                v = (v >= 0.f) ? v : NEGS * v;
                Cf[(size_t)i * D2_ + j] = v;
            }
}

// ------------------------------------------------- merged graph-conv GEMMs
// x1 = leaky(y1 @ g1), x2 = leaky(y2 @ g2) in one launch (blockIdx.z picks).
// 128-row blocks, acc[4][4]/wave — the BEST-MEASURED gc config (present in
// both best totals 392/401; the R4 64-row split correlated with ~+10 us).
__global__ __launch_bounds__(256, 1) void gemm_gc(
    const unsigned short* __restrict__ A1h, const unsigned short* __restrict__ A1l,
    const unsigned short* __restrict__ A2h, const unsigned short* __restrict__ A2l,
    const unsigned short* __restrict__ G1h, const unsigned short* __restrict__ G1l,
    const unsigned short* __restrict__ G2h, const unsigned short* __restrict__ G2l,
    float* __restrict__ X1, float* __restrict__ X2)
{
    const int z = blockIdx.z;
    const unsigned short* Ah = z ? A2h : A1h;
    const unsigned short* Al = z ? A2l : A1l;
    const unsigned short* Bh = z ? G2h : G1h;
    const unsigned short* Bl = z ? G2l : G1l;
    float* Cf = z ? X2 : X1;
    const int lda = DHP, ldb = DHP;
    const int row0 = blockIdx.y * 128, col0 = 0;
    const int wave = threadIdx.x >> 6, lane = threadIdx.x & 63;
    const int r0 = row0 + (wave >> 1) * 64, c0 = col0 + (wave & 1) * 64;
    const int q = lane >> 4, m = lane & 15;
    f32x4 acc[4][4];
#pragma unroll
    for (int a = 0; a < 4; ++a)
#pragma unroll
        for (int c = 0; c < 4; ++c) acc[a][c] = (f32x4){0.f, 0.f, 0.f, 0.f};
    bf16x8 ah0[4], al0[4], bh0[4], bl0[4];
    bf16x8 ah1[4], al1[4], bh1[4], bl1[4];
    LOADK(0, 0)
    int k0 = 0;
    for (; k0 + 64 <= DHP; k0 += 64) {
        LOADK(1, k0 + 32)
        MFMAK(0)
        if (k0 + 64 < DHP) { LOADK(0, k0 + 64) }
        MFMAK(1)
    }
    if (k0 < DHP) { MFMAK(0) }   // K=288 tail
#pragma unroll
    for (int mi = 0; mi < 4; ++mi)
#pragma unroll
        for (int nj = 0; nj < 4; ++nj)
#pragma unroll
            for (int t = 0; t < 4; ++t) {
                int i = r0 + mi*16 + q*4 + t;
                int j = c0 + nj*16 + m;
                float v = acc[mi][nj][t];
                v = (v >= 0.f) ? v : NEGS * v;
                Cf[(size_t)i * DG_ + j] = v;
            }
}

// ------------------------------------------------- xy via bf16 MFMA (upper tri)
// Only observable effect: which pairs pass x2>0.8. Off-diag xy huge vs band
// [1,1.026]; bf16 error negligible -> classification identical to fp32/f64.
#define XLOAD(S, k0) \
    _Pragma("unroll") \
    for (int t = 0; t < 4; ++t) { \
        af##S[t] = *(const bf16x8*)(base + (size_t)(r0 + t*16 + m) * DHP + (k0) + q*8); \
        bf##S[t] = *(const bf16x8*)(base + (size_t)(c0 + t*16 + m) * DHP + (k0) + q*8); \
    }
#define XMFMA(S) \
    _Pragma("unroll") \
    for (int mi = 0; mi < 4; ++mi) \
        _Pragma("unroll") \
        for (int nj = 0; nj < 4; ++nj) \
            acc[mi][nj] = __builtin_amdgcn_mfma_f32_16x16x32_bf16(af##S[mi], bf##S[nj], acc[mi][nj], 0, 0, 0);

__global__ __launch_bounds__(256, 1) void k_xy_mfma(
    const unsigned short* __restrict__ pxb, const float* __restrict__ px,
    const int* __restrict__ seq, float* __restrict__ den, float* __restrict__ accb)
{
    const int b = blockIdx.z;
    const int bx = blockIdx.x, by = blockIdx.y;
    if (bx < by) return;
    const int nb = seq[b];
    const int row0 = by * 128, col0 = bx * 128;
    if (row0 >= nb || col0 >= nb) return;
    const int wave = threadIdx.x >> 6, lane = threadIdx.x & 63;
    const int r0 = row0 + (wave >> 1) * 64, c0 = col0 + (wave & 1) * 64;
    if (c0 + 63 < r0 || r0 >= nb || c0 >= nb) return;   // wave-uniform exits
    const unsigned short* base = pxb + (size_t)b * TT * DHP;
    const int q = lane >> 4, m = lane & 15;
    f32x4 acc[4][4];
#pragma unroll
    for (int a = 0; a < 4; ++a)
#pragma unroll
        for (int c = 0; c < 4; ++c) acc[a][c] = (f32x4){0.f, 0.f, 0.f, 0.f};
    bf16x8 af0[4], bf0[4], af1[4], bf1[4];
    XLOAD(0, 0)
    int k0 = 0;
    for (; k0 + 64 <= DHP; k0 += 64) {
        XLOAD(1, k0 + 32)
        XMFMA(0)
        if (k0 + 64 < DHP) { XLOAD(0, k0 + 64) }
        XMFMA(1)
    }
    if (k0 < DHP) { XMFMA(0) }
    const float* b32 = px + (size_t)b * TT * DHP;
    float cj[4], ci[4][4];
#pragma unroll
    for (int nj = 0; nj < 4; ++nj) cj[nj] = b32[(size_t)(c0 + nj*16 + m) * DHP];
#pragma unroll
    for (int mi = 0; mi < 4; ++mi)
#pragma unroll
        for (int t = 0; t < 4; ++t) ci[mi][t] = b32[(size_t)(r0 + mi*16 + q*4 + t) * DHP];
#pragma unroll
    for (int mi = 0; mi < 4; ++mi)
#pragma unroll
        for (int nj = 0; nj < 4; ++nj)
#pragma unroll
            for (int t = 0; t < 4; ++t) {
                int i = r0 + mi*16 + q*4 + t;
                int j = c0 + nj*16 + m;
                if (i < j && j < nb) {
                    float xyv = 2.f * ci[mi][t] * cj[nj] - acc[mi][nj][t];
                    float xym = fmaxf(xyv, 1.0f);
                    // xym >= 1.026 => x2 <= 0.798 < 0.8: no correction
                    if (xym < 1.026f) {
                        float dd = logf(xym + sqrtf(xym * xym - 1.0f + 1e-7f));
                        dd = fminf(fmaxf(dd, 1e-6f), 200.0f);
                        float x2v = expf(-dd);
                        if (x2v > 0.8f) {
                            float w = expf(x2v) - 1.0f;
                            atomicAdd(&den[b * TT + i], w);
                            atomicAdd(&den[b * TT + j], w);
                            const float* pi = b32 + (size_t)i * DHP;
                            const float* pj = b32 + (size_t)j * DHP;
                            float* ai = accb + ((size_t)(b * TT + i)) * DHP;
                            float* aj = accb + ((size_t)(b * TT + j)) * DHP;
                            for (int d = 0; d < DHP; ++d) {
                                atomicAdd(&ai[d], w * pj[d]);
                                atomicAdd(&aj[d], w * pi[d]);
                            }
                        }
                    }
                }
            }
}

// ------------------------------------------------- expmap0 (px fp32 + bf16)
// also zeroes this row's accb slice (accb overwrites C1, dead after MLP2).
__global__ __launch_bounds__(256) void k_proj(
    const float* __restrict__ C2, const float* __restrict__ inputs,
    float* __restrict__ px, unsigned short* __restrict__ pxb,
    float* __restrict__ accb)
{
    const int r = blockIdx.x;
    const int tid = threadIdx.x;
    float v = (tid < 128) ? C2[(size_t)r * 128 + tid]
                          : inputs[(size_t)r * 1152 + 1024 + (tid - 128)];
    float sq = v * v;
#pragma unroll
    for (int o = 32; o > 0; o >>= 1) sq += __shfl_down(sq, o, 64);
    __shared__ float wred[4];
    __shared__ float cs[2];
    if ((tid & 63) == 0) wred[tid >> 6] = sq;
    __syncthreads();
    if (tid == 0) {
        float n2 = fmaxf(wred[0] + wred[1] + wred[2] + wred[3], 1e-12f);
        float n = sqrtf(n2);
        cs[0] = coshf(n);
        cs[1] = sinhf(n) / n;
    }
    __syncthreads();
    float sv = cs[1] * v;
    px[(size_t)r * DHP + 1 + tid] = sv;
    pxb[(size_t)r * DHP + 1 + tid] = f2bf(sv);
    if (tid == 0) {
        px[(size_t)r * DHP] = cs[0];
        pxb[(size_t)r * DHP] = f2bf(cs[0]);
    }
    if (tid < DHP - DH_) {   // 31 pad zeros
        px[(size_t)r * DHP + DH_ + tid] = 0.f;
        pxb[(size_t)r * DHP + DH_ + tid] = 0;
    }
    float* ab = accb + (size_t)r * DHP;
    ab[tid] = 0.f;
    if (tid < DHP - 256) ab[256 + tid] = 0.f;
}

// ------------------------------------------------- per-batch valid column sum
__global__ __launch_bounds__(256) void k_ssum(
    const float* __restrict__ px, const int* __restrict__ seq,
    float* __restrict__ S)
{
    const int b = blockIdx.x, chunk = blockIdx.y, tid = threadIdx.x;
    const int nb = seq[b];
    const int j0 = chunk * 32;
    const int j1 = (j0 + 32 < nb) ? j0 + 32 : nb;
    float a0 = 0.f, a1 = 0.f;
    const bool hasB = (tid < DHP - 256);
    for (int j = j0; j < j1; ++j) {
        const float* row = px + ((size_t)(b * TT + j)) * DHP;
        a0 += row[tid];
        if (hasB) a1 += row[256 + tid];
    }
    if (j1 > j0) {
        atomicAdd(&S[b * DHP + tid], a0);
        if (hasB) atomicAdd(&S[b * DHP + 256 + tid], a1);
    }
}

// ------------------------------------------------- Y1 = (S + corr + wd*px)/den
// emits split bf16 for the downstream MFMA graph-conv
__global__ void k_y1(const float* __restrict__ accb, const float* __restrict__ S,
                     const float* __restrict__ den, const int* __restrict__ seq,
                     const float* __restrict__ px,
                     unsigned short* __restrict__ yh, unsigned short* __restrict__ yl)
{
    size_t idx = (size_t)blockIdx.x * 256 + threadIdx.x;
    if (idx >= NPX) return;
    int r = (int)(idx / DHP);
    int b = r >> 11, i = r & (TT - 1);
    int d = (int)(idx - (size_t)r * DHP);
    float out = 0.f;
    if (i < seq[b])
        out = (S[b * DHP + d] + accb[idx] + diag_w() * px[idx]) / den[r];
    unsigned short hh = f2bf(out);
    yh[idx] = hh;
    yl[idx] = f2bf(out - bf2f(hh));
}

// ------------------------------------------------- disadj @ px via dual scan
// disadj[i,j] = r^|i-j|: full matvec = fwd + bwd first-order recursions.
__global__ __launch_bounds__(256) void k_band(
    const float* __restrict__ px,
    unsigned short* __restrict__ yh, unsigned short* __restrict__ yl)
{
    __shared__ float Fs[CH][DHP];   // 73,728 B
    const int b = blockIdx.y;
    const int i0 = blockIdx.x * CH;
    const int tid = threadIdx.x;
    const bool hasB = (tid < DHP - 256);
    const float r = expf(-INV_E);
    const float* base = px + (size_t)b * TT * DHP;

    // forward scan with left halo (batched)
    {
        const int jlo = (i0 - HALO > 0) ? i0 - HALO : 0;   // length mult of UB
        float LA = 0.f, LB = 0.f;
        for (int j = jlo; j < i0 + CH; j += UB) {
            float va[UB], vb[UB];
#pragma unroll
            for (int u = 0; u < UB; ++u) {
                const float* row = base + (size_t)(j + u) * DHP;
                va[u] = row[tid];
                vb[u] = hasB ? row[256 + tid] : 0.f;
            }
#pragma unroll
            for (int u = 0; u < UB; ++u) {
                LA = fmaf(r, LA, va[u]);
                LB = fmaf(r, LB, vb[u]);
                const int jj = j + u;
                if (jj >= i0) {
                    Fs[jj - i0][tid] = LA;
                    if (hasB) Fs[jj - i0][256 + tid] = LB;
                }
            }
        }
    }
    __syncthreads();
    // backward: halo warmup (batched), then chunk phase with emit
    {
        const int jhi = (i0 + CH - 1 + HALO < TT - 1) ? i0 + CH - 1 + HALO : TT - 1;
        float RA = 0.f, RB = 0.f;
        int j = jhi;
        for (; j >= i0 + CH; j -= UB) {    // warmup length mult of UB
            float va[UB], vb[UB];
#pragma unroll
            for (int u = 0; u < UB; ++u) {
                const float* row = base + (size_t)(j - u) * DHP;
                va[u] = row[tid];
                vb[u] = hasB ? row[256 + tid] : 0.f;
            }
#pragma unroll
            for (int u = 0; u < UB; ++u) {
                RA = fmaf(r, RA, va[u]);
                RB = fmaf(r, RB, vb[u]);
            }
        }
        for (; j >= i0; j -= UB) {         // chunk phase: emit every row
            float va[UB], vb[UB];
#pragma unroll
            for (int u = 0; u < UB; ++u) {
                const float* row = base + (size_t)(j - u) * DHP;
                va[u] = row[tid];
                vb[u] = hasB ? row[256 + tid] : 0.f;
            }
#pragma unroll
            for (int u = 0; u < UB; ++u) {
                const int jj = j - u;
                RA = fmaf(r, RA, va[u]);
                RB = fmaf(r, RB, vb[u]);
                size_t o = ((size_t)(b * TT + jj)) * DHP + tid;
                float ya = Fs[jj - i0][tid] + RA - va[u];
                unsigned short hh = f2bf(ya);
                yh[o] = hh; yl[o] = f2bf(ya - bf2f(hh));
                if (hasB) {
                    float yb = Fs[jj - i0][256 + tid] + RB - vb[u];
                    size_t ob = o + 256;
                    unsigned short h2 = f2bf(yb);
                    yh[ob] = h2; yl[ob] = f2bf(yb - bf2f(h2));
                }
            }
        }
    }
}

// ------------------------------------------------- frame_prob
__global__ __launch_bounds__(256) void k_frame(
    const float* __restrict__ x1, const float* __restrict__ x2f,
    const float* __restrict__ cls_w, const float* __restrict__ cls_b,
    float* __restrict__ dout)
{
    const int r = blockIdx.x * 4 + (threadIdx.x >> 6);
    const int lane = threadIdx.x & 63;
    float s = 0.f;
#pragma unroll
    for (int t = 0; t < 2; ++t) {
        int g = lane + t * 64;
        float cw1 = cls_w[g];
        if (g == 0) cw1 = -cw1;      // signs: only dim 0 negated
        s += x1[(size_t)r * DG_ + g] * cw1;
        s += x2f[(size_t)r * DG_ + g] * cls_w[DG_ + g];
    }
#pragma unroll
    for (int o = 32; o > 0; o >>= 1) s += __shfl_down(s, o, 64);
    if (lane == 0) dout[8 + r] = 2.0f + 2.0f * s + cls_b[0];
}

// ------------------------------------------------- top-k MIL (bitonic sort)
__global__ __launch_bounds__(1024) void k_clas(
    const int* __restrict__ seq, float* __restrict__ dout)
{
    __shared__ float s[TT];
    const int b = blockIdx.x, tid = threadIdx.x;
    const int nb = seq[b];
    for (int t = tid; t < TT; t += 1024)
        s[t] = (t < nb) ? dout[8 + b * TT + t] : -1e30f;
    __syncthreads();
    for (int k = 2; k <= TT; k <<= 1)
        for (int j = k >> 1; j > 0; j >>= 1) {
            for (int i = tid; i < TT; i += 1024) {
                int ixj = i ^ j;
                if (ixj > i) {
                    float a = s[i], c = s[ixj];
                    bool descBlk = ((i & k) == 0);
                    if (descBlk ? (a < c) : (a > c)) { s[i] = c; s[ixj] = a; }
                }
            }
            __syncthreads();
        }
    const int kk = nb / 16 + 1;
    float part = 0.f;
    for (int t = tid; t < kk; t += 1024) part += s[t];
#pragma unroll
    for (int o = 32; o > 0; o >>= 1) part += __shfl_down(part, o, 64);
    __shared__ float wred[16];
    if ((tid & 63) == 0) wred[tid >> 6] = part;
    __syncthreads();
    if (tid == 0) {
        float mil = 0.f;
#pragma unroll
        for (int t = 0; t < 16; ++t) mil += wred[t];
        mil /= (float)kk;
        dout[b] = 1.f / (1.f + expf(-mil));
    }
}

// ---------------------------------------------------------------- launch
extern "C" void kernel_launch(void* const* d_in, const int* in_sizes, int n_in,
                              void* d_out, int out_size, void* d_ws, size_t ws_size,
                              hipStream_t stream) {
    (void)in_sizes; (void)n_in; (void)out_size; (void)ws_size;
    const float* inputs = (const float*)d_in[0];
    const int*   seq    = (const int*)d_in[1];
    const float* w1     = (const float*)d_in[2];
    const float* b1     = (const float*)d_in[3];
    const float* w2     = (const float*)d_in[4];
    const float* b2     = (const float*)d_in[5];
    const float* gw1    = (const float*)d_in[6];
    const float* gw2    = (const float*)d_in[7];
    const float* cls_w  = (const float*)d_in[8];
    const float* cls_b  = (const float*)d_in[9];
    float* dout = (float*)d_out;
    float* ws = (float*)d_ws;

    // o_big region: px + pxb + y2 + y1
    float* px  = ws + o_big;
    unsigned short* pxb = (unsigned short*)(ws + o_big + 4718592);
    unsigned short* y2h = (unsigned short*)(ws + o_big + 7077888);
    unsigned short* y2l = y2h + NPX;
    unsigned short* y1h = (unsigned short*)(ws + o_big + 11796480);
    unsigned short* y1l = y1h + NPX;
    // o_c1 region: C1h/C1l -> accb + x1
    unsigned short* C1h = (unsigned short*)(ws + o_c1);
    unsigned short* C1l = C1h + (size_t)MTOT * D1_;
    float* accb = ws + o_c1;
    float* x1   = ws + o_c1 + 4718592;
    // o_c2 region: C2 -> x2f
    float* C2  = ws + o_c2;
    float* x2f = ws + o_c2;
    // weights
    unsigned short* wsS = (unsigned short*)(ws + o_w);
    unsigned short *W1h = wsS + sw_w1h, *W1l = wsS + sw_w1l;
    unsigned short *W2h = wsS + sw_w2h, *W2l = wsS + sw_w2l;
    unsigned short *g1h = wsS + sw_g1h, *g1l = wsS + sw_g1l;
    unsigned short *g2h = wsS + sw_g2h, *g2l = wsS + sw_g2l;
    float* S   = ws + o_S;
    float* den = ws + o_den;

    // merged init + weight splits (1 dispatch, was 3)
    k_setup<<<928, 256, 0, stream>>>(den, seq, S, w1, w2, W1h, W1l, W2h, W2l,
                                     gw1, gw2, g1h, g1l, g2h, g2l);

    // MLP1: R3 best-measured config (512-thr, 128x128, BKC=32, B direct)
    gemm_mlp1<<<512, 512, 0, stream>>>(inputs, W1h, W1l, b1, C1h, C1l);
    // MLP2: 64-row tiles -> 256 blocks
    gemm_mlp2<<<256, 256, 0, stream>>>(C1h, C1l, W2h, W2l, b2, C2);

    // expmap0 (px/pxb overwrite o_big) + accb zeroing (C1 dead after MLP2)
    k_proj<<<MTOT, 256, 0, stream>>>(C2, inputs, px, pxb, accb);

    // valid column sums
    k_ssum<<<dim3(BB, TT / 32), 256, 0, stream>>>(px, seq, S);

    // Lorentz similarity via bf16 MFMA, upper triangle
    k_xy_mfma<<<dim3(TT / 128, TT / 128, BB), 256, 0, stream>>>(pxb, px, seq, den, accb);

    // Y1 = (S + corr + diag)/den -> split bf16 (separate pass: best-measured)
    k_y1<<<(int)(NPX / 256), 256, 0, stream>>>(accb, S, den, seq, px, y1h, y1l);

    // disadj @ px via batched dual scan -> split bf16 y2
    k_band<<<dim3(TT / CH, BB), 256, 0, stream>>>(px, y2h, y2l);

    // merged graph-conv projections via MFMA: 128-row tiles (best-measured)
    gemm_gc<<<dim3(1, MTOT / 128, 2), 256, 0, stream>>>(
        y1h, y1l, y2h, y2l, g1h, g1l, g2h, g2l, x1, x2f);

    // frame_prob + MIL
    k_frame<<<MTOT / 4, 256, 0, stream>>>(x1, x2f, cls_w, cls_b, dout);
    k_clas<<<BB, 1024, 0, stream>>>(seq, dout);
}

// Round 10
// 377.919 us; speedup vs baseline: 1.2116x; 1.0462x over previous
//
#include <hip/hip_runtime.h>
#include <math.h>

// ---------------------------------------------------------------- constants
#define BB 8
#define TT 2048
#define DV_ 1024
#define DA_ 128
#define D1_ 512
#define D2_ 128
#define DH_ 257
#define DHP 288            // padded (zeros): divisible by 32 for MFMA K-chunks
#define DG_ 128
#define MTOT (BB*TT)       // 16384 rows
#define NPX ((size_t)MTOT*DHP)

#define NEGS 0.01f
#define INV_E 0.36787944117144233f
#define CH 64              // scan chunk rows
#define HALO 64            // r^64 ~ 6e-11 rel: truncation ~2e-6 abs on px~3e4 —
                           // far below the reference's own fp32 rounding
#define UB 8               // scan batch: 8 rows of loads issued together

#define RS 40              // MLP1 LDS row stride (hw): 80 B -> 20-bank step/row
#define BKC 32             // MLP1 K-chunk (halfwords) — R3 best-measured config

// ---------------------------------------------------------------- workspace
static const size_t o_big = 0;                     // 16,777,216 f
static const size_t o_c1  = 16777216;              //  8,388,608 f
static const size_t o_c2  = o_c1 + 8388608;        //  2,097,152 f
static const size_t o_w   = o_c2 + 2097152;        //    663,552 f (split weights)
static const size_t o_S   = o_w + 663552;          //      2,304 f
static const size_t o_den = o_S + 2304;            //     16,384 f

// short offsets inside o_w
static const size_t sw_w1h = 0;          // 524,288
static const size_t sw_w1l = 524288;
static const size_t sw_w2h = 1048576;    // 65,536
static const size_t sw_w2l = 1114112;
static const size_t sw_g1h = 1179648;    // 36,864 ([128][288])
static const size_t sw_g1l = 1216512;
static const size_t sw_g2h = 1253376;
static const size_t sw_g2l = 1290240;

typedef __attribute__((ext_vector_type(8))) __bf16 bf16x8;
typedef __attribute__((ext_vector_type(8))) unsigned short us8;
typedef __attribute__((ext_vector_type(4))) float f32x4;

__device__ __forceinline__ float diag_w() {
    // identical fp32 ops to the generic path evaluated at xy == 1.0f
    float dd = logf(1.0f + sqrtf(1.0f*1.0f - 1.0f + 1e-7f));
    dd = fminf(fmaxf(dd, 1e-6f), 200.0f);
    float x2 = expf(-dd);
    return expf(x2) - 1.0f;
}

__device__ __forceinline__ unsigned short f2bf(float f) {
    unsigned int u = __float_as_uint(f);
    u += 0x7FFFu + ((u >> 16) & 1u);   // RNE
    return (unsigned short)(u >> 16);
}
__device__ __forceinline__ float bf2f(unsigned short h) {
    return __uint_as_float((unsigned int)h << 16);
}

// 8 fp32 -> split (hi,lo) bf16x8 — byte-identical math to the old k_split_in
__device__ __forceinline__ void cvt8(const float4 a, const float4 b,
                                     us8& h, us8& l) {
    unsigned short hh;
#define CV_(idx, val) hh = f2bf(val); h[idx] = hh; l[idx] = f2bf((val) - bf2f(hh));
    CV_(0, a.x) CV_(1, a.y) CV_(2, a.z) CV_(3, a.w)
    CV_(4, b.x) CV_(5, b.y) CV_(6, b.z) CV_(7, b.w)
#undef CV_
}

// ---------------------------------------------------------------- setup
// merged: den/S init + w1/w2 split + gw1/gw2 transpose-pad-split, one launch.
__global__ void k_setup(float* __restrict__ den, const int* __restrict__ seq,
                        float* __restrict__ S,
                        const float* __restrict__ w1, const float* __restrict__ w2,
                        unsigned short* __restrict__ h1, unsigned short* __restrict__ l1,
                        unsigned short* __restrict__ h2, unsigned short* __restrict__ l2,
                        const float* __restrict__ g1, const float* __restrict__ g2,
                        unsigned short* __restrict__ gh1, unsigned short* __restrict__ gl1,
                        unsigned short* __restrict__ gh2, unsigned short* __restrict__ gl2)
{
    const int bx = blockIdx.x;
    if (bx < 64) {
        int r = bx * 256 + threadIdx.x;   // 16384 total
        den[r] = (float)seq[r >> 11] + diag_w();
        if (r < BB * DHP) S[r] = 0.f;
    } else if (bx < 640) {
        size_t i = ((size_t)(bx - 64) * 256 + threadIdx.x) * 4;
        const float* src; unsigned short *h, *l; size_t o;
        if (i < (size_t)D1_ * DV_) { src = w1; h = h1; l = l1; o = i; }
        else {
            o = i - (size_t)D1_ * DV_;
            if (o >= (size_t)D2_ * D1_) return;
            src = w2; h = h2; l = l2;
        }
        float4 v = *(const float4*)(src + o);
        ushort4 hv, lv;
        hv.x = f2bf(v.x); lv.x = f2bf(v.x - bf2f(hv.x));
        hv.y = f2bf(v.y); lv.y = f2bf(v.y - bf2f(hv.y));
        hv.z = f2bf(v.z); lv.z = f2bf(v.z - bf2f(hv.z));
        hv.w = f2bf(v.w); lv.w = f2bf(v.w - bf2f(hv.w));
        *(ushort4*)(h + o) = hv;
        *(ushort4*)(l + o) = lv;
    } else {
        const int bb = bx - 640;          // 0..287
        const int zz = (bb >= 144);
        int i = (bb - (zz ? 144 : 0)) * 256 + threadIdx.x;   // DG*DHP = 36864
        if (i >= DG_ * DHP) return;
        const float* g = zz ? g2 : g1;
        unsigned short* th = zz ? gh2 : gh1;
        unsigned short* tl = zz ? gl2 : gl1;
        int c = i / DHP, k = i - c * DHP;
        float v = (k < DH_) ? g[k * DG_ + c] : 0.f;
        unsigned short hh = f2bf(v);
        th[i] = hh;
        tl[i] = f2bf(v - bf2f(hh));
    }
}

// ------------------------------------------------- MLP1: LDS-staged split GEMM
// BEST-MEASURED variant (R3/R8/R9: 94.5-98 us): 512-thr blocks, 128x128 tile,
// BKC=32, A fp32-direct + in-reg (hi,lo) split, B (L2-resident split W1)
// register double-buffered straight from global, LDS holds only A (40 KB).
// UNTOUCHED this round (6 structural levers all landed 95-105 us @ ~21% Mfma).
__global__ __launch_bounds__(512, 2) void gemm_mlp1(
    const float* __restrict__ inA,
    const unsigned short* __restrict__ Bh, const unsigned short* __restrict__ Bl,
    const float* __restrict__ bias,
    unsigned short* __restrict__ Ch, unsigned short* __restrict__ Cl)
{
    __shared__ unsigned short sm[2][2][128 * RS];   // [buf][Ah,Al] = 40 KB
    const int ib = blockIdx.x;               // 512 blocks
    const int x = ib & 7, slot = ib >> 3;    // xcd lane, 64 slots
    const int cc = slot & 3, g = slot >> 2;  // col-tile, panel group
    const int row0 = (x + 8 * g) * 128, col0 = cc * 128;
    const int tid = threadIdx.x;
    const int wave = tid >> 6, lane = tid & 63;
    const int r0w = (wave >> 2) * 64;                 // block-local row base
    const int c0 = col0 + (wave & 3) * 32;            // GLOBAL col base
    const int q = lane >> 4, m = lane & 15;
    // staging: thread covers row srow, 8-elem col slice
    const int srow = tid >> 2, scol = (tid & 3) << 3;
    const size_t gA0 = (size_t)(row0 + srow) * 1152 + scol;        // fp32 elems
    const int s0 = srow * RS + scol;
    // B fragment bases (global halfword offsets), static-indexed
    size_t bo_[2];
#pragma unroll
    for (int t = 0; t < 2; ++t) bo_[t] = (size_t)(c0 + t*16 + m) * DV_ + q*8;

    float4 a00, a01;
    bf16x8 fah[4], fal[4];
    bf16x8 bh0[2], bl0[2], bh1[2], bl1[2];

#define M1_LDGA(o) { \
    a00 = *(const float4*)(inA + gA0 + (o)); a01 = *(const float4*)(inA + gA0 + (o) + 4); }
#define M1_STAGE(BUF) { \
    us8 h_, l_; \
    cvt8(a00, a01, h_, l_); \
    *(us8*)&sm[BUF][0][s0] = h_; *(us8*)&sm[BUF][1][s0] = l_; }
#define M1_LDGB(S, o) \
    _Pragma("unroll") \
    for (int t = 0; t < 2; ++t) { \
        bh##S[t] = *(const bf16x8*)(Bh + bo_[t] + (o)); \
        bl##S[t] = *(const bf16x8*)(Bl + bo_[t] + (o)); }
#define M1_LOADA(BUF) \
    _Pragma("unroll") \
    for (int t = 0; t < 4; ++t) { \
        const int ra = (r0w + t*16 + m) * RS + q*8; \
        fah[t] = *(const bf16x8*)&sm[BUF][0][ra]; \
        fal[t] = *(const bf16x8*)&sm[BUF][1][ra]; }
#define M1_MFMA(S) \
    _Pragma("unroll") \
    for (int mi = 0; mi < 4; ++mi) \
        _Pragma("unroll") \
        for (int nj = 0; nj < 2; ++nj) { \
            acc[mi][nj] = __builtin_amdgcn_mfma_f32_16x16x32_bf16(fah[mi], bh##S[nj], acc[mi][nj], 0, 0, 0); \
            acc[mi][nj] = __builtin_amdgcn_mfma_f32_16x16x32_bf16(fal[mi], bh##S[nj], acc[mi][nj], 0, 0, 0); \
            acc[mi][nj] = __builtin_amdgcn_mfma_f32_16x16x32_bf16(fah[mi], bl##S[nj], acc[mi][nj], 0, 0, 0); \
        }

    f32x4 acc[4][2];
#pragma unroll
    for (int a = 0; a < 4; ++a)
#pragma unroll
        for (int c = 0; c < 2; ++c) acc[a][c] = (f32x4){0.f, 0.f, 0.f, 0.f};

    // prologue: chunk 0 -> sm[0], b0
    M1_LDGA(0)
    M1_STAGE(0)
    M1_LDGB(0, 0)
    __syncthreads();

    const int NI = (DV_ / BKC) / 2;   // 16 double-chunk iterations
    for (int i = 0; i < NI; ++i) {
        // even chunk 2i: A in sm[0], B in b0
        const size_t o1 = (size_t)(2*i + 1) * BKC;
        M1_LDGA(o1)          // prefetch A chunk 2i+1
        M1_LDGB(1, o1)       // prefetch B chunk 2i+1
        M1_LOADA(0)
        M1_MFMA(0)
        M1_STAGE(1)          // stage A chunk 2i+1
        __syncthreads();
        // odd chunk 2i+1: A in sm[1], B in b1
        if (i + 1 < NI) {
            const size_t o2 = (size_t)(2*i + 2) * BKC;
            M1_LDGA(o2)
            M1_LDGB(0, o2)
        }
        M1_LOADA(1)
        M1_MFMA(1)
        if (i + 1 < NI) { M1_STAGE(0) }
        __syncthreads();
    }
#undef M1_LDGA
#undef M1_STAGE
#undef M1_LDGB
#undef M1_LOADA
#undef M1_MFMA

    float bj[2];
#pragma unroll
    for (int nj = 0; nj < 2; ++nj) bj[nj] = bias[c0 + nj*16 + m];
#pragma unroll
    for (int mi = 0; mi < 4; ++mi)
#pragma unroll
        for (int nj = 0; nj < 2; ++nj)
#pragma unroll
            for (int t = 0; t < 4; ++t) {
                int i = row0 + r0w + mi*16 + q*4 + t;
                int j = c0 + nj*16 + m;
                float v = acc[mi][nj][t] + bj[nj];
                v = (v >= 0.f) ? v : NEGS * v;
                size_t o = (size_t)i * D1_ + j;
                unsigned short hh = f2bf(v);
                Ch[o] = hh;
                Cl[o] = f2bf(v - bf2f(hh));
            }
}

// ------------------------------------------------- split-bf16x3 MFMA cores
// 128-row-tile core: 4 A frags, 4 B frags (used by gemm_gc — best-measured)
#define LOADK(S, k0) \
    _Pragma("unroll") \
    for (int t = 0; t < 4; ++t) { \
        size_t ao = (size_t)(r0 + t*16 + m) * lda + (k0) + q*8; \
        size_t bo = (size_t)(c0 + t*16 + m) * ldb + (k0) + q*8; \
        ah##S[t] = *(const bf16x8*)(Ah + ao); \
        al##S[t] = *(const bf16x8*)(Al + ao); \
        bh##S[t] = *(const bf16x8*)(Bh + bo); \
        bl##S[t] = *(const bf16x8*)(Bl + bo); \
    }
#define MFMAK(S) \
    _Pragma("unroll") \
    for (int mi = 0; mi < 4; ++mi) \
        _Pragma("unroll") \
        for (int nj = 0; nj < 4; ++nj) { \
            acc[mi][nj] = __builtin_amdgcn_mfma_f32_16x16x32_bf16(ah##S[mi], bh##S[nj], acc[mi][nj], 0, 0, 0); \
            acc[mi][nj] = __builtin_amdgcn_mfma_f32_16x16x32_bf16(al##S[mi], bh##S[nj], acc[mi][nj], 0, 0, 0); \
            acc[mi][nj] = __builtin_amdgcn_mfma_f32_16x16x32_bf16(ah##S[mi], bl##S[nj], acc[mi][nj], 0, 0, 0); \
        }

// 64-row-tile core: 4 A frags, 2 B frags, stride LD (used by MLP2)
#define LOADK2(S, k0, LD) \
    _Pragma("unroll") \
    for (int t = 0; t < 4; ++t) { \
        size_t ao = (size_t)(r0 + t*16 + m) * (LD) + (k0) + q*8; \
        ah##S[t] = *(const bf16x8*)(Ah + ao); \
        al##S[t] = *(const bf16x8*)(Al + ao); \
    } \
    _Pragma("unroll") \
    for (int t = 0; t < 2; ++t) { \
        size_t bo = (size_t)(c0 + t*16 + m) * (LD) + (k0) + q*8; \
        bh##S[t] = *(const bf16x8*)(Bh + bo); \
        bl##S[t] = *(const bf16x8*)(Bl + bo); \
    }
#define MFMAK2(S) \
    _Pragma("unroll") \
    for (int mi = 0; mi < 4; ++mi) \
        _Pragma("unroll") \
        for (int nj = 0; nj < 2; ++nj) { \
            acc[mi][nj] = __builtin_amdgcn_mfma_f32_16x16x32_bf16(ah##S[mi], bh##S[nj], acc[mi][nj], 0, 0, 0); \
            acc[mi][nj] = __builtin_amdgcn_mfma_f32_16x16x32_bf16(al##S[mi], bh##S[nj], acc[mi][nj], 0, 0, 0); \
            acc[mi][nj] = __builtin_amdgcn_mfma_f32_16x16x32_bf16(ah##S[mi], bl##S[nj], acc[mi][nj], 0, 0, 0); \
        }

// MLP2: 64-row blocks x 128 cols, wave = 64x32 tile. 256 blocks.
__global__ __launch_bounds__(256, 1) void gemm_mlp2(
    const unsigned short* __restrict__ Ah, const unsigned short* __restrict__ Al,
    const unsigned short* __restrict__ Bh, const unsigned short* __restrict__ Bl,
    const float* __restrict__ bias, float* __restrict__ Cf)
{
    const int row0 = blockIdx.x * 64;        // 256 blocks
    const int wave = threadIdx.x >> 6, lane = threadIdx.x & 63;
    const int r0 = row0, c0 = wave * 32;
    const int q = lane >> 4, m = lane & 15;
    f32x4 acc[4][2];
#pragma unroll
    for (int a = 0; a < 4; ++a)
#pragma unroll
        for (int c = 0; c < 2; ++c) acc[a][c] = (f32x4){0.f, 0.f, 0.f, 0.f};
    bf16x8 ah0[4], al0[4], bh0[2], bl0[2];
    bf16x8 ah1[4], al1[4], bh1[2], bl1[2];
    LOADK2(0, 0, D1_)
    for (int k0 = 0; k0 + 64 <= D1_; k0 += 64) {
        LOADK2(1, k0 + 32, D1_)
        MFMAK2(0)
        if (k0 + 64 < D1_) { LOADK2(0, k0 + 64, D1_) }
        MFMAK2(1)
    }
    float bj[2];
#pragma unroll
    for (int nj = 0; nj < 2; ++nj) bj[nj] = bias[c0 + nj*16 + m];
#pragma unroll
    for (int mi = 0; mi < 4; ++mi)
#pragma unroll
        for (int nj = 0; nj < 2; ++nj)
#pragma unroll
            for (int t = 0; t < 4; ++t) {
                int i = r0 + mi*16 + q*4 + t;
                int j = c0 + nj*16 + m;
                float v = acc[mi][nj][t] + bj[nj];
                v = (v >= 0.f) ? v : NEGS * v;
                Cf[(size_t)i * D2_ + j] = v;
            }
}

// ------------------------------------------------- merged graph-conv GEMMs
// x1 = leaky(y1 @ g1), x2 = leaky(y2 @ g2) in one launch (blockIdx.z picks).
// 128-row blocks, acc[4][4]/wave — the BEST-MEASURED gc config.
__global__ __launch_bounds__(256, 1) void gemm_gc(
    const unsigned short* __restrict__ A1h, const unsigned short* __restrict__ A1l,
    const unsigned short* __restrict__ A2h, const unsigned short* __restrict__ A2l,
    const unsigned short* __restrict__ G1h, const unsigned short* __restrict__ G1l,
    const unsigned short* __restrict__ G2h, const unsigned short* __restrict__ G2l,
    float* __restrict__ X1, float* __restrict__ X2)
{
    const int z = blockIdx.z;
    const unsigned short* Ah = z ? A2h : A1h;
    const unsigned short* Al = z ? A2l : A1l;
    const unsigned short* Bh = z ? G2h : G1h;
    const unsigned short* Bl = z ? G2l : G1l;
    float* Cf = z ? X2 : X1;
    const int lda = DHP, ldb = DHP;
    const int row0 = blockIdx.y * 128, col0 = 0;
    const int wave = threadIdx.x >> 6, lane = threadIdx.x & 63;
    const int r0 = row0 + (wave >> 1) * 64, c0 = col0 + (wave & 1) * 64;
    const int q = lane >> 4, m = lane & 15;
    f32x4 acc[4][4];
#pragma unroll
    for (int a = 0; a < 4; ++a)
#pragma unroll
        for (int c = 0; c < 4; ++c) acc[a][c] = (f32x4){0.f, 0.f, 0.f, 0.f};
    bf16x8 ah0[4], al0[4], bh0[4], bl0[4];
    bf16x8 ah1[4], al1[4], bh1[4], bl1[4];
    LOADK(0, 0)
    int k0 = 0;
    for (; k0 + 64 <= DHP; k0 += 64) {
        LOADK(1, k0 + 32)
        MFMAK(0)
        if (k0 + 64 < DHP) { LOADK(0, k0 + 64) }
        MFMAK(1)
    }
    if (k0 < DHP) { MFMAK(0) }   // K=288 tail
#pragma unroll
    for (int mi = 0; mi < 4; ++mi)
#pragma unroll
        for (int nj = 0; nj < 4; ++nj)
#pragma unroll
            for (int t = 0; t < 4; ++t) {
                int i = r0 + mi*16 + q*4 + t;
                int j = c0 + nj*16 + m;
                float v = acc[mi][nj][t];
                v = (v >= 0.f) ? v : NEGS * v;
                Cf[(size_t)i * DG_ + j] = v;
            }
}

// ------------------------------------------------- xy via bf16 MFMA (upper tri)
#define XLOAD(S, k0) \
    _Pragma("unroll") \
    for (int t = 0; t < 4; ++t) { \
        af##S[t] = *(const bf16x8*)(base + (size_t)(r0 + t*16 + m) * DHP + (k0) + q*8); \
        bf##S[t] = *(const bf16x8*)(base + (size_t)(c0 + t*16 + m) * DHP + (k0) + q*8); \
    }
#define XMFMA(S) \
    _Pragma("unroll") \
    for (int mi = 0; mi < 4; ++mi) \
        _Pragma("unroll") \
        for (int nj = 0; nj < 4; ++nj) \
            acc[mi][nj] = __builtin_amdgcn_mfma_f32_16x16x32_bf16(af##S[mi], bf##S[nj], acc[mi][nj], 0, 0, 0);

__global__ __launch_bounds__(256, 1) void k_xy_mfma(
    const unsigned short* __restrict__ pxb, const float* __restrict__ px,
    const int* __restrict__ seq, float* __restrict__ den, float* __restrict__ accb)
{
    const int b = blockIdx.z;
    const int bx = blockIdx.x, by = blockIdx.y;
    if (bx < by) return;
    const int nb = seq[b];
    const int row0 = by * 128, col0 = bx * 128;
    if (row0 >= nb || col0 >= nb) return;
    const int wave = threadIdx.x >> 6, lane = threadIdx.x & 63;
    const int r0 = row0 + (wave >> 1) * 64, c0 = col0 + (wave & 1) * 64;
    if (c0 + 63 < r0 || r0 >= nb || c0 >= nb) return;   // wave-uniform exits
    const unsigned short* base = pxb + (size_t)b * TT * DHP;
    const int q = lane >> 4, m = lane & 15;
    f32x4 acc[4][4];
#pragma unroll
    for (int a = 0; a < 4; ++a)
#pragma unroll
        for (int c = 0; c < 4; ++c) acc[a][c] = (f32x4){0.f, 0.f, 0.f, 0.f};
    bf16x8 af0[4], bf0[4], af1[4], bf1[4];
    XLOAD(0, 0)
    int k0 = 0;
    for (; k0 + 64 <= DHP; k0 += 64) {
        XLOAD(1, k0 + 32)
        XMFMA(0)
        if (k0 + 64 < DHP) { XLOAD(0, k0 + 64) }
        XMFMA(1)
    }
    if (k0 < DHP) { XMFMA(0) }
    const float* b32 = px + (size_t)b * TT * DHP;
    float cj[4], ci[4][4];
#pragma unroll
    for (int nj = 0; nj < 4; ++nj) cj[nj] = b32[(size_t)(c0 + nj*16 + m) * DHP];
#pragma unroll
    for (int mi = 0; mi < 4; ++mi)
#pragma unroll
        for (int t = 0; t < 4; ++t) ci[mi][t] = b32[(size_t)(r0 + mi*16 + q*4 + t) * DHP];
#pragma unroll
    for (int mi = 0; mi < 4; ++mi)
#pragma unroll
        for (int nj = 0; nj < 4; ++nj)
#pragma unroll
            for (int t = 0; t < 4; ++t) {
                int i = r0 + mi*16 + q*4 + t;
                int j = c0 + nj*16 + m;
                if (i < j && j < nb) {
                    float xyv = 2.f * ci[mi][t] * cj[nj] - acc[mi][nj][t];
                    float xym = fmaxf(xyv, 1.0f);
                    // xym >= 1.026 => x2 <= 0.798 < 0.8: no correction
                    if (xym < 1.026f) {
                        float dd = logf(xym + sqrtf(xym * xym - 1.0f + 1e-7f));
                        dd = fminf(fmaxf(dd, 1e-6f), 200.0f);
                        float x2v = expf(-dd);
                        if (x2v > 0.8f) {
                            float w = expf(x2v) - 1.0f;
                            atomicAdd(&den[b * TT + i], w);
                            atomicAdd(&den[b * TT + j], w);
                            const float* pi = b32 + (size_t)i * DHP;
                            const float* pj = b32 + (size_t)j * DHP;
                            float* ai = accb + ((size_t)(b * TT + i)) * DHP;
                            float* aj = accb + ((size_t)(b * TT + j)) * DHP;
                            for (int d = 0; d < DHP; ++d) {
                                atomicAdd(&ai[d], w * pj[d]);
                                atomicAdd(&aj[d], w * pi[d]);
                            }
                        }
                    }
                }
            }
}

// ------------------------------------------------- expmap0 (px fp32 + bf16)
// R10: WAVE-PER-ROW — 4 rows per 256-thr block, each wave owns one row with
// 4 elems/lane + shfl_xor butterfly; NO barriers, no single-thread serial
// section (cosh/sinh computed redundantly per lane — VALU-cheap). Also zeroes
// this row's accb slice. (n2 summation order differs by ulps from the old
// tree — 1000x below the bf16 error already accepted downstream.)
__global__ __launch_bounds__(256) void k_proj(
    const float* __restrict__ C2, const float* __restrict__ inputs,
    float* __restrict__ px, unsigned short* __restrict__ pxb,
    float* __restrict__ accb)
{
    const int r = blockIdx.x * 4 + (threadIdx.x >> 6);
    const int l = threadIdx.x & 63;
    float v[4];
#pragma unroll
    for (int e = 0; e < 2; ++e)              // dims 0..127 from C2
        v[e] = C2[(size_t)r * 128 + l + 64*e];
#pragma unroll
    for (int e = 2; e < 4; ++e)              // dims 128..255 from inputs tail
        v[e] = inputs[(size_t)r * 1152 + 1024 + (l + 64*e - 128)];
    float sq = v[0]*v[0] + v[1]*v[1] + v[2]*v[2] + v[3]*v[3];
#pragma unroll
    for (int o = 32; o > 0; o >>= 1) sq += __shfl_xor(sq, o, 64);
    float n2 = fmaxf(sq, 1e-12f);
    float n = sqrtf(n2);
    float cs0 = coshf(n);
    float cs1 = sinhf(n) / n;
    const size_t base = (size_t)r * DHP;
#pragma unroll
    for (int e = 0; e < 4; ++e) {
        int idx = l + 64*e;
        float sv = cs1 * v[e];
        px[base + 1 + idx] = sv;
        pxb[base + 1 + idx] = f2bf(sv);
        accb[base + idx] = 0.f;
    }
    if (l == 0) { px[base] = cs0; pxb[base] = f2bf(cs0); }
    if (l < DHP - DH_) { px[base + DH_ + l] = 0.f; pxb[base + DH_ + l] = 0; }
    if (l < 32) accb[base + 256 + l] = 0.f;
}

// ------------------------------------------------- per-batch valid column sum
__global__ __launch_bounds__(256) void k_ssum(
    const float* __restrict__ px, const int* __restrict__ seq,
    float* __restrict__ S)
{
    const int b = blockIdx.x, chunk = blockIdx.y, tid = threadIdx.x;
    const int nb = seq[b];
    const int j0 = chunk * 32;
    const int j1 = (j0 + 32 < nb) ? j0 + 32 : nb;
    float a0 = 0.f, a1 = 0.f;
    const bool hasB = (tid < DHP - 256);
    for (int j = j0; j < j1; ++j) {
        const float* row = px + ((size_t)(b * TT + j)) * DHP;
        a0 += row[tid];
        if (hasB) a1 += row[256 + tid];
    }
    if (j1 > j0) {
        atomicAdd(&S[b * DHP + tid], a0);
        if (hasB) atomicAdd(&S[b * DHP + 256 + tid], a1);
    }
}

// ------------------------------------------------- Y1 = (S + corr + wd*px)/den
__global__ void k_y1(const float* __restrict__ accb, const float* __restrict__ S,
                     const float* __restrict__ den, const int* __restrict__ seq,
                     const float* __restrict__ px,
                     unsigned short* __restrict__ yh, unsigned short* __restrict__ yl)
{
    size_t idx = (size_t)blockIdx.x * 256 + threadIdx.x;
    if (idx >= NPX) return;
    int r = (int)(idx / DHP);
    int b = r >> 11, i = r & (TT - 1);
    int d = (int)(idx - (size_t)r * DHP);
    float out = 0.f;
    if (i < seq[b])
        out = (S[b * DHP + d] + accb[idx] + diag_w() * px[idx]) / den[r];
    unsigned short hh = f2bf(out);
    yh[idx] = hh;
    yl[idx] = f2bf(out - bf2f(hh));
}

// ------------------------------------------------- disadj @ px via dual scan
// R10: D-SPLIT — dims are independent across the row-scan, so blockIdx.z
// splits the 288 dims into two 144-halves: 512 blocks (2x parallelism on a
// latency-bound kernel). Per-dim fmaf sequence unchanged -> bit-identical y2.
__global__ __launch_bounds__(192) void k_band(
    const float* __restrict__ px,
    unsigned short* __restrict__ yh, unsigned short* __restrict__ yl)
{
    __shared__ float Fs[CH][144];   // per-thread indexed scan buffer, 36,864 B
    const int b = blockIdx.y;
    const int i0 = blockIdx.x * CH;
    const int tid = threadIdx.x;
    const int d = blockIdx.z * 144 + tid;
    const bool act = (tid < 144);
    const float r = expf(-INV_E);
    const float* base = px + (size_t)b * TT * DHP;

    // forward scan with left halo (batched)
    if (act) {
        const int jlo = (i0 - HALO > 0) ? i0 - HALO : 0;   // length mult of UB
        float LA = 0.f;
        for (int j = jlo; j < i0 + CH; j += UB) {
            float va[UB];
#pragma unroll
            for (int u = 0; u < UB; ++u)
                va[u] = base[(size_t)(j + u) * DHP + d];
#pragma unroll
            for (int u = 0; u < UB; ++u) {
                LA = fmaf(r, LA, va[u]);
                const int jj = j + u;
                if (jj >= i0) Fs[jj - i0][tid] = LA;
            }
        }
    }
    // (no barrier needed: Fs[.][tid] is written and read by the same thread)
    // backward: halo warmup (batched), then chunk phase with emit
    if (act) {
        const int jhi = (i0 + CH - 1 + HALO < TT - 1) ? i0 + CH - 1 + HALO : TT - 1;
        float RA = 0.f;
        int j = jhi;
        for (; j >= i0 + CH; j -= UB) {    // warmup length mult of UB
            float va[UB];
#pragma unroll
            for (int u = 0; u < UB; ++u)
                va[u] = base[(size_t)(j - u) * DHP + d];
#pragma unroll
            for (int u = 0; u < UB; ++u) RA = fmaf(r, RA, va[u]);
        }
        for (; j >= i0; j -= UB) {         // chunk phase: emit every row
            float va[UB];
#pragma unroll
            for (int u = 0; u < UB; ++u)
                va[u] = base[(size_t)(j - u) * DHP + d];
#pragma unroll
            for (int u = 0; u < UB; ++u) {
                const int jj = j - u;
                RA = fmaf(r, RA, va[u]);
                size_t o = ((size_t)(b * TT + jj)) * DHP + d;
                float ya = Fs[jj - i0][tid] + RA - va[u];
                unsigned short hh = f2bf(ya);
                yh[o] = hh; yl[o] = f2bf(ya - bf2f(hh));
            }
        }
    }
}

// ------------------------------------------------- frame_prob
__global__ __launch_bounds__(256) void k_frame(
    const float* __restrict__ x1, const float* __restrict__ x2f,
    const float* __restrict__ cls_w, const float* __restrict__ cls_b,
    float* __restrict__ dout)
{
    const int r = blockIdx.x * 4 + (threadIdx.x >> 6);
    const int lane = threadIdx.x & 63;
    float s = 0.f;
#pragma unroll
    for (int t = 0; t < 2; ++t) {
        int g = lane + t * 64;
        float cw1 = cls_w[g];
        if (g == 0) cw1 = -cw1;      // signs: only dim 0 negated
        s += x1[(size_t)r * DG_ + g] * cw1;
        s += x2f[(size_t)r * DG_ + g] * cls_w[DG_ + g];
    }
#pragma unroll
    for (int o = 32; o > 0; o >>= 1) s += __shfl_down(s, o, 64);
    if (lane == 0) dout[8 + r] = 2.0f + 2.0f * s + cls_b[0];
}

// ------------------------------------------------- top-k MIL via radix select
// R10: the bitonic full sort (66 barrier-passes) is overkill — we only need
// the sum of the top kk <= 129 values. 4-pass MSD radix select on the
// sign-flipped uint ordering finds the kk-th largest value T exactly; then
// sum = sum_{u>T} f + (kk - count_gt) * f(T) (tie-exact in value, sum order
// differs — as the bitonic version's tree-sum already did vs the reference).
__global__ __launch_bounds__(1024) void k_clas(
    const int* __restrict__ seq, float* __restrict__ dout)
{
    __shared__ unsigned su[TT];
    __shared__ unsigned hist[256];
    __shared__ unsigned sh_prefix;
    __shared__ int sh_rem;
    __shared__ float wred[16];
    __shared__ int wcnt[16];
    const int b = blockIdx.x, tid = threadIdx.x;
    const int nb = seq[b];
    const int kk = nb / 16 + 1;
    // load + order-preserving transform (f>=0: bits|MSB; f<0: ~bits)
    for (int t = tid; t < TT; t += 1024) {
        unsigned u = 0u;   // invalid rows -> 0, below any valid transform
        if (t < nb) {
            unsigned x = __float_as_uint(dout[8 + b * TT + t]);
            u = (x & 0x80000000u) ? ~x : (x | 0x80000000u);
        }
        su[t] = u;
    }
    if (tid == 0) { sh_prefix = 0u; sh_rem = kk; }
    __syncthreads();
#pragma unroll
    for (int p = 0; p < 4; ++p) {
        const int shift = 24 - 8 * p;
        const unsigned hm = (p == 0) ? 0u : (0xFFFFFFFFu << (shift + 8));
        if (tid < 256) hist[tid] = 0u;
        __syncthreads();
        const unsigned pref = sh_prefix;
        for (int t = tid; t < TT; t += 1024) {
            unsigned u = su[t];
            if (u != 0u && (u & hm) == pref)
                atomicAdd(&hist[(u >> shift) & 0xFFu], 1u);
        }
        __syncthreads();
        if (tid == 0) {
            int rem = sh_rem;
            int v = 255;
            for (; v > 0; --v) {
                int c = (int)hist[v];
                if (c < rem) rem -= c;
                else break;
            }
            sh_rem = rem;
            sh_prefix = sh_prefix | ((unsigned)v << shift);
        }
        __syncthreads();
    }
    const unsigned T = sh_prefix;   // kk-th largest (transformed)
    float fsum = 0.f; int cnt = 0;
    for (int t = tid; t < TT; t += 1024) {
        unsigned u = su[t];
        if (u > T) {
            unsigned x = (u & 0x80000000u) ? (u ^ 0x80000000u) : ~u;
            fsum += __uint_as_float(x);
            ++cnt;
        }
    }
#pragma unroll
    for (int o = 32; o > 0; o >>= 1) {
        fsum += __shfl_down(fsum, o, 64);
        cnt  += __shfl_down(cnt, o, 64);
    }
    if ((tid & 63) == 0) { wred[tid >> 6] = fsum; wcnt[tid >> 6] = cnt; }
    __syncthreads();
    if (tid == 0) {
        float s = 0.f; int c = 0;
#pragma unroll
        for (int t = 0; t < 16; ++t) { s += wred[t]; c += wcnt[t]; }
        unsigned x = (T & 0x80000000u) ? (T ^ 0x80000000u) : ~T;
        s += (float)(kk - c) * __uint_as_float(x);   // tied-at-threshold share
        float mil = s / (float)kk;
        dout[b] = 1.f / (1.f + expf(-mil));
    }
}

// ---------------------------------------------------------------- launch
extern "C" void kernel_launch(void* const* d_in, const int* in_sizes, int n_in,
                              void* d_out, int out_size, void* d_ws, size_t ws_size,
                              hipStream_t stream) {
    (void)in_sizes; (void)n_in; (void)out_size; (void)ws_size;
    const float* inputs = (const float*)d_in[0];
    const int*   seq    = (const int*)d_in[1];
    const float* w1     = (const float*)d_in[2];
    const float* b1     = (const float*)d_in[3];
    const float* w2     = (const float*)d_in[4];
    const float* b2     = (const float*)d_in[5];
    const float* gw1    = (const float*)d_in[6];
    const float* gw2    = (const float*)d_in[7];
    const float* cls_w  = (const float*)d_in[8];
    const float* cls_b  = (const float*)d_in[9];
    float* dout = (float*)d_out;
    float* ws = (float*)d_ws;

    // o_big region: px + pxb + y2 + y1
    float* px  = ws + o_big;
    unsigned short* pxb = (unsigned short*)(ws + o_big + 4718592);
    unsigned short* y2h = (unsigned short*)(ws + o_big + 7077888);
    unsigned short* y2l = y2h + NPX;
    unsigned short* y1h = (unsigned short*)(ws + o_big + 11796480);
    unsigned short* y1l = y1h + NPX;
    // o_c1 region: C1h/C1l -> accb + x1
    unsigned short* C1h = (unsigned short*)(ws + o_c1);
    unsigned short* C1l = C1h + (size_t)MTOT * D1_;
    float* accb = ws + o_c1;
    float* x1   = ws + o_c1 + 4718592;
    // o_c2 region: C2 -> x2f
    float* C2  = ws + o_c2;
    float* x2f = ws + o_c2;
    // weights
    unsigned short* wsS = (unsigned short*)(ws + o_w);
    unsigned short *W1h = wsS + sw_w1h, *W1l = wsS + sw_w1l;
    unsigned short *W2h = wsS + sw_w2h, *W2l = wsS + sw_w2l;
    unsigned short *g1h = wsS + sw_g1h, *g1l = wsS + sw_g1l;
    unsigned short *g2h = wsS + sw_g2h, *g2l = wsS + sw_g2l;
    float* S   = ws + o_S;
    float* den = ws + o_den;

    // merged init + weight splits (1 dispatch)
    k_setup<<<928, 256, 0, stream>>>(den, seq, S, w1, w2, W1h, W1l, W2h, W2l,
                                     gw1, gw2, g1h, g1l, g2h, g2l);

    // MLP1: R3 best-measured config (512-thr, 128x128, BKC=32, B direct)
    gemm_mlp1<<<512, 512, 0, stream>>>(inputs, W1h, W1l, b1, C1h, C1l);
    // MLP2: 64-row tiles -> 256 blocks
    gemm_mlp2<<<256, 256, 0, stream>>>(C1h, C1l, W2h, W2l, b2, C2);

    // expmap0: wave-per-row (4 rows/block, no barriers) + accb zeroing
    k_proj<<<MTOT / 4, 256, 0, stream>>>(C2, inputs, px, pxb, accb);

    // valid column sums
    k_ssum<<<dim3(BB, TT / 32), 256, 0, stream>>>(px, seq, S);

    // Lorentz similarity via bf16 MFMA, upper triangle
    k_xy_mfma<<<dim3(TT / 128, TT / 128, BB), 256, 0, stream>>>(pxb, px, seq, den, accb);

    // Y1 = (S + corr + diag)/den -> split bf16
    k_y1<<<(int)(NPX / 256), 256, 0, stream>>>(accb, S, den, seq, px, y1h, y1l);

    // disadj @ px via batched dual scan, D-split (2x parallelism) -> y2
    k_band<<<dim3(TT / CH, BB, 2), 192, 0, stream>>>(px, y2h, y2l);

    // merged graph-conv projections via MFMA: 128-row tiles (best-measured)
    gemm_gc<<<dim3(1, MTOT / 128, 2), 256, 0, stream>>>(
        y1h, y1l, y2h, y2l, g1h, g1l, g2h, g2l, x1, x2f);

    // frame_prob + MIL (radix top-k select)
    k_frame<<<MTOT / 4, 256, 0, stream>>>(x1, x2f, cls_w, cls_b, dout);
    k_clas<<<BB, 1024, 0, stream>>>(seq, dout);
}

// Round 11
// 372.471 us; speedup vs baseline: 1.2294x; 1.0146x over previous
//
#include <hip/hip_runtime.h>
#include <math.h>

// ---------------------------------------------------------------- constants
#define BB 8
#define TT 2048
#define DV_ 1024
#define DA_ 128
#define D1_ 512
#define D2_ 128
#define DH_ 257
#define DHP 288            // padded (zeros): divisible by 32 for MFMA K-chunks
#define DG_ 128
#define MTOT (BB*TT)       // 16384 rows
#define NPX ((size_t)MTOT*DHP)

#define NEGS 0.01f
#define INV_E 0.36787944117144233f
#define CH 64              // scan chunk rows
#define HALO 64            // r^64 ~ 6e-11 rel: truncation ~2e-6 abs on px~3e4 —
                           // far below the reference's own fp32 rounding
#define UB 8               // scan batch: 8 rows of loads issued together

#define RS 40              // MLP1 LDS row stride (hw): 80 B -> 20-bank step/row
#define BKC 32             // MLP1 K-chunk (halfwords) — R3 best-measured config

// ---------------------------------------------------------------- workspace
static const size_t o_big = 0;                     // 16,777,216 f
static const size_t o_c1  = 16777216;              //  8,388,608 f
static const size_t o_c2  = o_c1 + 8388608;        //  2,097,152 f
static const size_t o_w   = o_c2 + 2097152;        //    663,552 f (split weights)
static const size_t o_S   = o_w + 663552;          //      2,304 f
static const size_t o_den = o_S + 2304;            //     16,384 f

// short offsets inside o_w
static const size_t sw_w1h = 0;          // 524,288
static const size_t sw_w1l = 524288;
static const size_t sw_w2h = 1048576;    // 65,536
static const size_t sw_w2l = 1114112;
static const size_t sw_g1h = 1179648;    // 36,864 ([128][288])
static const size_t sw_g1l = 1216512;
static const size_t sw_g2h = 1253376;
static const size_t sw_g2l = 1290240;

typedef __attribute__((ext_vector_type(8))) __bf16 bf16x8;
typedef __attribute__((ext_vector_type(8))) unsigned short us8;
typedef __attribute__((ext_vector_type(4))) float f32x4;

__device__ __forceinline__ float diag_w() {
    // identical fp32 ops to the generic path evaluated at xy == 1.0f
    float dd = logf(1.0f + sqrtf(1.0f*1.0f - 1.0f + 1e-7f));
    dd = fminf(fmaxf(dd, 1e-6f), 200.0f);
    float x2 = expf(-dd);
    return expf(x2) - 1.0f;
}

__device__ __forceinline__ unsigned short f2bf(float f) {
    unsigned int u = __float_as_uint(f);
    u += 0x7FFFu + ((u >> 16) & 1u);   // RNE
    return (unsigned short)(u >> 16);
}
__device__ __forceinline__ float bf2f(unsigned short h) {
    return __uint_as_float((unsigned int)h << 16);
}

// 8 fp32 -> split (hi,lo) bf16x8 — byte-identical math to the old k_split_in
__device__ __forceinline__ void cvt8(const float4 a, const float4 b,
                                     us8& h, us8& l) {
    unsigned short hh;
#define CV_(idx, val) hh = f2bf(val); h[idx] = hh; l[idx] = f2bf((val) - bf2f(hh));
    CV_(0, a.x) CV_(1, a.y) CV_(2, a.z) CV_(3, a.w)
    CV_(4, b.x) CV_(5, b.y) CV_(6, b.z) CV_(7, b.w)
#undef CV_
}

// ---------------------------------------------------------------- setup
// merged: den/S init + w1/w2 split + gw1/gw2 transpose-pad-split, one launch.
__global__ void k_setup(float* __restrict__ den, const int* __restrict__ seq,
                        float* __restrict__ S,
                        const float* __restrict__ w1, const float* __restrict__ w2,
                        unsigned short* __restrict__ h1, unsigned short* __restrict__ l1,
                        unsigned short* __restrict__ h2, unsigned short* __restrict__ l2,
                        const float* __restrict__ g1, const float* __restrict__ g2,
                        unsigned short* __restrict__ gh1, unsigned short* __restrict__ gl1,
                        unsigned short* __restrict__ gh2, unsigned short* __restrict__ gl2)
{
    const int bx = blockIdx.x;
    if (bx < 64) {
        int r = bx * 256 + threadIdx.x;   // 16384 total
        den[r] = (float)seq[r >> 11] + diag_w();
        if (r < BB * DHP) S[r] = 0.f;
    } else if (bx < 640) {
        size_t i = ((size_t)(bx - 64) * 256 + threadIdx.x) * 4;
        const float* src; unsigned short *h, *l; size_t o;
        if (i < (size_t)D1_ * DV_) { src = w1; h = h1; l = l1; o = i; }
        else {
            o = i - (size_t)D1_ * DV_;
            if (o >= (size_t)D2_ * D1_) return;
            src = w2; h = h2; l = l2;
        }
        float4 v = *(const float4*)(src + o);
        ushort4 hv, lv;
        hv.x = f2bf(v.x); lv.x = f2bf(v.x - bf2f(hv.x));
        hv.y = f2bf(v.y); lv.y = f2bf(v.y - bf2f(hv.y));
        hv.z = f2bf(v.z); lv.z = f2bf(v.z - bf2f(hv.z));
        hv.w = f2bf(v.w); lv.w = f2bf(v.w - bf2f(hv.w));
        *(ushort4*)(h + o) = hv;
        *(ushort4*)(l + o) = lv;
    } else {
        const int bb = bx - 640;          // 0..287
        const int zz = (bb >= 144);
        int i = (bb - (zz ? 144 : 0)) * 256 + threadIdx.x;   // DG*DHP = 36864
        if (i >= DG_ * DHP) return;
        const float* g = zz ? g2 : g1;
        unsigned short* th = zz ? gh2 : gh1;
        unsigned short* tl = zz ? gl2 : gl1;
        int c = i / DHP, k = i - c * DHP;
        float v = (k < DH_) ? g[k * DG_ + c] : 0.f;
        unsigned short hh = f2bf(v);
        th[i] = hh;
        tl[i] = f2bf(v - bf2f(hh));
    }
}

// ------------------------------------------------- MLP1: LDS-staged split GEMM
// BEST-MEASURED variant (R3/R8/R9/R10: 94.5-98 us): 512-thr blocks, 128x128
// tile, BKC=32, A fp32-direct + in-reg (hi,lo) split, B (L2-resident split W1)
// register double-buffered straight from global, LDS holds only A (40 KB).
__global__ __launch_bounds__(512, 2) void gemm_mlp1(
    const float* __restrict__ inA,
    const unsigned short* __restrict__ Bh, const unsigned short* __restrict__ Bl,
    const float* __restrict__ bias,
    unsigned short* __restrict__ Ch, unsigned short* __restrict__ Cl)
{
    __shared__ unsigned short sm[2][2][128 * RS];   // [buf][Ah,Al] = 40 KB
    const int ib = blockIdx.x;               // 512 blocks
    const int x = ib & 7, slot = ib >> 3;    // xcd lane, 64 slots
    const int cc = slot & 3, g = slot >> 2;  // col-tile, panel group
    const int row0 = (x + 8 * g) * 128, col0 = cc * 128;
    const int tid = threadIdx.x;
    const int wave = tid >> 6, lane = tid & 63;
    const int r0w = (wave >> 2) * 64;                 // block-local row base
    const int c0 = col0 + (wave & 3) * 32;            // GLOBAL col base
    const int q = lane >> 4, m = lane & 15;
    // staging: thread covers row srow, 8-elem col slice
    const int srow = tid >> 2, scol = (tid & 3) << 3;
    const size_t gA0 = (size_t)(row0 + srow) * 1152 + scol;        // fp32 elems
    const int s0 = srow * RS + scol;
    // B fragment bases (global halfword offsets), static-indexed
    size_t bo_[2];
#pragma unroll
    for (int t = 0; t < 2; ++t) bo_[t] = (size_t)(c0 + t*16 + m) * DV_ + q*8;

    float4 a00, a01;
    bf16x8 fah[4], fal[4];
    bf16x8 bh0[2], bl0[2], bh1[2], bl1[2];

#define M1_LDGA(o) { \
    a00 = *(const float4*)(inA + gA0 + (o)); a01 = *(const float4*)(inA + gA0 + (o) + 4); }
#define M1_STAGE(BUF) { \
    us8 h_, l_; \
    cvt8(a00, a01, h_, l_); \
    *(us8*)&sm[BUF][0][s0] = h_; *(us8*)&sm[BUF][1][s0] = l_; }
#define M1_LDGB(S, o) \
    _Pragma("unroll") \
    for (int t = 0; t < 2; ++t) { \
        bh##S[t] = *(const bf16x8*)(Bh + bo_[t] + (o)); \
        bl##S[t] = *(const bf16x8*)(Bl + bo_[t] + (o)); }
#define M1_LOADA(BUF) \
    _Pragma("unroll") \
    for (int t = 0; t < 4; ++t) { \
        const int ra = (r0w + t*16 + m) * RS + q*8; \
        fah[t] = *(const bf16x8*)&sm[BUF][0][ra]; \
        fal[t] = *(const bf16x8*)&sm[BUF][1][ra]; }
#define M1_MFMA(S) \
    _Pragma("unroll") \
    for (int mi = 0; mi < 4; ++mi) \
        _Pragma("unroll") \
        for (int nj = 0; nj < 2; ++nj) { \
            acc[mi][nj] = __builtin_amdgcn_mfma_f32_16x16x32_bf16(fah[mi], bh##S[nj], acc[mi][nj], 0, 0, 0); \
            acc[mi][nj] = __builtin_amdgcn_mfma_f32_16x16x32_bf16(fal[mi], bh##S[nj], acc[mi][nj], 0, 0, 0); \
            acc[mi][nj] = __builtin_amdgcn_mfma_f32_16x16x32_bf16(fah[mi], bl##S[nj], acc[mi][nj], 0, 0, 0); \
        }

    f32x4 acc[4][2];
#pragma unroll
    for (int a = 0; a < 4; ++a)
#pragma unroll
        for (int c = 0; c < 2; ++c) acc[a][c] = (f32x4){0.f, 0.f, 0.f, 0.f};

    // prologue: chunk 0 -> sm[0], b0
    M1_LDGA(0)
    M1_STAGE(0)
    M1_LDGB(0, 0)
    __syncthreads();

    const int NI = (DV_ / BKC) / 2;   // 16 double-chunk iterations
    for (int i = 0; i < NI; ++i) {
        // even chunk 2i: A in sm[0], B in b0
        const size_t o1 = (size_t)(2*i + 1) * BKC;
        M1_LDGA(o1)          // prefetch A chunk 2i+1
        M1_LDGB(1, o1)       // prefetch B chunk 2i+1
        M1_LOADA(0)
        M1_MFMA(0)
        M1_STAGE(1)          // stage A chunk 2i+1
        __syncthreads();
        // odd chunk 2i+1: A in sm[1], B in b1
        if (i + 1 < NI) {
            const size_t o2 = (size_t)(2*i + 2) * BKC;
            M1_LDGA(o2)
            M1_LDGB(0, o2)
        }
        M1_LOADA(1)
        M1_MFMA(1)
        if (i + 1 < NI) { M1_STAGE(0) }
        __syncthreads();
    }
#undef M1_LDGA
#undef M1_STAGE
#undef M1_LDGB
#undef M1_LOADA
#undef M1_MFMA

    float bj[2];
#pragma unroll
    for (int nj = 0; nj < 2; ++nj) bj[nj] = bias[c0 + nj*16 + m];
#pragma unroll
    for (int mi = 0; mi < 4; ++mi)
#pragma unroll
        for (int nj = 0; nj < 2; ++nj)
#pragma unroll
            for (int t = 0; t < 4; ++t) {
                int i = row0 + r0w + mi*16 + q*4 + t;
                int j = c0 + nj*16 + m;
                float v = acc[mi][nj][t] + bj[nj];
                v = (v >= 0.f) ? v : NEGS * v;
                size_t o = (size_t)i * D1_ + j;
                unsigned short hh = f2bf(v);
                Ch[o] = hh;
                Cl[o] = f2bf(v - bf2f(hh));
            }
}

// ------------------------------------------------- split-bf16x3 MFMA cores
// 128-row-tile core: 4 A frags, 4 B frags (used by gemm_gc — best-measured)
#define LOADK(S, k0) \
    _Pragma("unroll") \
    for (int t = 0; t < 4; ++t) { \
        size_t ao = (size_t)(r0 + t*16 + m) * lda + (k0) + q*8; \
        size_t bo = (size_t)(c0 + t*16 + m) * ldb + (k0) + q*8; \
        ah##S[t] = *(const bf16x8*)(Ah + ao); \
        al##S[t] = *(const bf16x8*)(Al + ao); \
        bh##S[t] = *(const bf16x8*)(Bh + bo); \
        bl##S[t] = *(const bf16x8*)(Bl + bo); \
    }
#define MFMAK(S) \
    _Pragma("unroll") \
    for (int mi = 0; mi < 4; ++mi) \
        _Pragma("unroll") \
        for (int nj = 0; nj < 4; ++nj) { \
            acc[mi][nj] = __builtin_amdgcn_mfma_f32_16x16x32_bf16(ah##S[mi], bh##S[nj], acc[mi][nj], 0, 0, 0); \
            acc[mi][nj] = __builtin_amdgcn_mfma_f32_16x16x32_bf16(al##S[mi], bh##S[nj], acc[mi][nj], 0, 0, 0); \
            acc[mi][nj] = __builtin_amdgcn_mfma_f32_16x16x32_bf16(ah##S[mi], bl##S[nj], acc[mi][nj], 0, 0, 0); \
        }

// 64-row-tile core: 4 A frags, 2 B frags, stride LD (used by MLP2)
#define LOADK2(S, k0, LD) \
    _Pragma("unroll") \
    for (int t = 0; t < 4; ++t) { \
        size_t ao = (size_t)(r0 + t*16 + m) * (LD) + (k0) + q*8; \
        ah##S[t] = *(const bf16x8*)(Ah + ao); \
        al##S[t] = *(const bf16x8*)(Al + ao); \
    } \
    _Pragma("unroll") \
    for (int t = 0; t < 2; ++t) { \
        size_t bo = (size_t)(c0 + t*16 + m) * (LD) + (k0) + q*8; \
        bh##S[t] = *(const bf16x8*)(Bh + bo); \
        bl##S[t] = *(const bf16x8*)(Bl + bo); \
    }
#define MFMAK2(S) \
    _Pragma("unroll") \
    for (int mi = 0; mi < 4; ++mi) \
        _Pragma("unroll") \
        for (int nj = 0; nj < 2; ++nj) { \
            acc[mi][nj] = __builtin_amdgcn_mfma_f32_16x16x32_bf16(ah##S[mi], bh##S[nj], acc[mi][nj], 0, 0, 0); \
            acc[mi][nj] = __builtin_amdgcn_mfma_f32_16x16x32_bf16(al##S[mi], bh##S[nj], acc[mi][nj], 0, 0, 0); \
            acc[mi][nj] = __builtin_amdgcn_mfma_f32_16x16x32_bf16(ah##S[mi], bl##S[nj], acc[mi][nj], 0, 0, 0); \
        }

// MLP2: 64-row blocks x 128 cols, wave = 64x32 tile. 256 blocks.
__global__ __launch_bounds__(256, 1) void gemm_mlp2(
    const unsigned short* __restrict__ Ah, const unsigned short* __restrict__ Al,
    const unsigned short* __restrict__ Bh, const unsigned short* __restrict__ Bl,
    const float* __restrict__ bias, float* __restrict__ Cf)
{
    const int row0 = blockIdx.x * 64;        // 256 blocks
    const int wave = threadIdx.x >> 6, lane = threadIdx.x & 63;
    const int r0 = row0, c0 = wave * 32;
    const int q = lane >> 4, m = lane & 15;
    f32x4 acc[4][2];
#pragma unroll
    for (int a = 0; a < 4; ++a)
#pragma unroll
        for (int c = 0; c < 2; ++c) acc[a][c] = (f32x4){0.f, 0.f, 0.f, 0.f};
    bf16x8 ah0[4], al0[4], bh0[2], bl0[2];
    bf16x8 ah1[4], al1[4], bh1[2], bl1[2];
    LOADK2(0, 0, D1_)
    for (int k0 = 0; k0 + 64 <= D1_; k0 += 64) {
        LOADK2(1, k0 + 32, D1_)
        MFMAK2(0)
        if (k0 + 64 < D1_) { LOADK2(0, k0 + 64, D1_) }
        MFMAK2(1)
    }
    float bj[2];
#pragma unroll
    for (int nj = 0; nj < 2; ++nj) bj[nj] = bias[c0 + nj*16 + m];
#pragma unroll
    for (int mi = 0; mi < 4; ++mi)
#pragma unroll
        for (int nj = 0; nj < 2; ++nj)
#pragma unroll
            for (int t = 0; t < 4; ++t) {
                int i = r0 + mi*16 + q*4 + t;
                int j = c0 + nj*16 + m;
                float v = acc[mi][nj][t] + bj[nj];
                v = (v >= 0.f) ? v : NEGS * v;
                Cf[(size_t)i * D2_ + j] = v;
            }
}

// ------------------------------------------------- merged graph-conv GEMMs
// x1 = leaky(y1 @ g1), x2 = leaky(y2 @ g2) in one launch (blockIdx.z picks).
// 128-row blocks, acc[4][4]/wave — the BEST-MEASURED gc config.
__global__ __launch_bounds__(256, 1) void gemm_gc(
    const unsigned short* __restrict__ A1h, const unsigned short* __restrict__ A1l,
    const unsigned short* __restrict__ A2h, const unsigned short* __restrict__ A2l,
    const unsigned short* __restrict__ G1h, const unsigned short* __restrict__ G1l,
    const unsigned short* __restrict__ G2h, const unsigned short* __restrict__ G2l,
    float* __restrict__ X1, float* __restrict__ X2)
{
    const int z = blockIdx.z;
    const unsigned short* Ah = z ? A2h : A1h;
    const unsigned short* Al = z ? A2l : A1l;
    const unsigned short* Bh = z ? G2h : G1h;
    const unsigned short* Bl = z ? G2l : G1l;
    float* Cf = z ? X2 : X1;
    const int lda = DHP, ldb = DHP;
    const int row0 = blockIdx.y * 128, col0 = 0;
    const int wave = threadIdx.x >> 6, lane = threadIdx.x & 63;
    const int r0 = row0 + (wave >> 1) * 64, c0 = col0 + (wave & 1) * 64;
    const int q = lane >> 4, m = lane & 15;
    f32x4 acc[4][4];
#pragma unroll
    for (int a = 0; a < 4; ++a)
#pragma unroll
        for (int c = 0; c < 4; ++c) acc[a][c] = (f32x4){0.f, 0.f, 0.f, 0.f};
    bf16x8 ah0[4], al0[4], bh0[4], bl0[4];
    bf16x8 ah1[4], al1[4], bh1[4], bl1[4];
    LOADK(0, 0)
    int k0 = 0;
    for (; k0 + 64 <= DHP; k0 += 64) {
        LOADK(1, k0 + 32)
        MFMAK(0)
        if (k0 + 64 < DHP) { LOADK(0, k0 + 64) }
        MFMAK(1)
    }
    if (k0 < DHP) { MFMAK(0) }   // K=288 tail
#pragma unroll
    for (int mi = 0; mi < 4; ++mi)
#pragma unroll
        for (int nj = 0; nj < 4; ++nj)
#pragma unroll
            for (int t = 0; t < 4; ++t) {
                int i = r0 + mi*16 + q*4 + t;
                int j = c0 + nj*16 + m;
                float v = acc[mi][nj][t];
                v = (v >= 0.f) ? v : NEGS * v;
                Cf[(size_t)i * DG_ + j] = v;
            }
}

// ------------------------------------------------- merged mid-phase
// ssum + xy + band are mutually independent (all read px/pxb, write disjoint
// S / accb+den / y2) but were 3 serialized dispatches. One flattened launch
// lets band's latency-bound scans and ssum's streaming hide under xy's MFMA.
// Block layout: [0,512) band, [512,1024) ssum, [1024,3072) xy. All 256-thr.
// Per-branch math identical to the R10 kernels -> outputs bit-identical.
#define XLOAD(S, k0) \
    _Pragma("unroll") \
    for (int t = 0; t < 4; ++t) { \
        af##S[t] = *(const bf16x8*)(base + (size_t)(r0 + t*16 + m) * DHP + (k0) + q*8); \
        bf##S[t] = *(const bf16x8*)(base + (size_t)(c0 + t*16 + m) * DHP + (k0) + q*8); \
    }
#define XMFMA(S) \
    _Pragma("unroll") \
    for (int mi = 0; mi < 4; ++mi) \
        _Pragma("unroll") \
        for (int nj = 0; nj < 4; ++nj) \
            acc[mi][nj] = __builtin_amdgcn_mfma_f32_16x16x32_bf16(af##S[mi], bf##S[nj], acc[mi][nj], 0, 0, 0);

__global__ __launch_bounds__(256, 1) void k_mid(
    const unsigned short* __restrict__ pxb, const float* __restrict__ px,
    const int* __restrict__ seq, float* __restrict__ den,
    float* __restrict__ accb, float* __restrict__ S,
    unsigned short* __restrict__ yh, unsigned short* __restrict__ yl)
{
    __shared__ float Fs[CH][144];   // band scan buffer (36,864 B)
    const int id = blockIdx.x;
    const int tid = threadIdx.x;

    if (id < 512) {
        // ---------------- band: disadj @ px via dual scan, D-split
        const int t_ = id;
        const int zz = t_ >> 8;            // 0..1 (dim half)
        const int b = (t_ >> 5) & 7;       // batch
        const int i0 = (t_ & 31) * CH;     // row chunk
        const int d = zz * 144 + tid;
        const bool act = (tid < 144);
        const float r = expf(-INV_E);
        const float* base = px + (size_t)b * TT * DHP;
        if (act) {
            const int jlo = (i0 - HALO > 0) ? i0 - HALO : 0;
            float LA = 0.f;
            for (int j = jlo; j < i0 + CH; j += UB) {
                float va[UB];
#pragma unroll
                for (int u = 0; u < UB; ++u)
                    va[u] = base[(size_t)(j + u) * DHP + d];
#pragma unroll
                for (int u = 0; u < UB; ++u) {
                    LA = fmaf(r, LA, va[u]);
                    const int jj = j + u;
                    if (jj >= i0) Fs[jj - i0][tid] = LA;
                }
            }
            const int jhi = (i0 + CH - 1 + HALO < TT - 1) ? i0 + CH - 1 + HALO : TT - 1;
            float RA = 0.f;
            int j = jhi;
            for (; j >= i0 + CH; j -= UB) {
                float va[UB];
#pragma unroll
                for (int u = 0; u < UB; ++u)
                    va[u] = base[(size_t)(j - u) * DHP + d];
#pragma unroll
                for (int u = 0; u < UB; ++u) RA = fmaf(r, RA, va[u]);
            }
            for (; j >= i0; j -= UB) {
                float va[UB];
#pragma unroll
                for (int u = 0; u < UB; ++u)
                    va[u] = base[(size_t)(j - u) * DHP + d];
#pragma unroll
                for (int u = 0; u < UB; ++u) {
                    const int jj = j - u;
                    RA = fmaf(r, RA, va[u]);
                    size_t o = ((size_t)(b * TT + jj)) * DHP + d;
                    float ya = Fs[jj - i0][tid] + RA - va[u];
                    unsigned short hh = f2bf(ya);
                    yh[o] = hh; yl[o] = f2bf(ya - bf2f(hh));
                }
            }
        }
        return;
    }
    if (id < 1024) {
        // ---------------- ssum: per-batch valid column sum
        const int t_ = id - 512;
        const int b = t_ >> 6, chunk = t_ & 63;
        const int nb = seq[b];
        const int j0 = chunk * 32;
        const int j1 = (j0 + 32 < nb) ? j0 + 32 : nb;
        float a0 = 0.f, a1 = 0.f;
        const bool hasB = (tid < DHP - 256);
        for (int j = j0; j < j1; ++j) {
            const float* row = px + ((size_t)(b * TT + j)) * DHP;
            a0 += row[tid];
            if (hasB) a1 += row[256 + tid];
        }
        if (j1 > j0) {
            atomicAdd(&S[b * DHP + tid], a0);
            if (hasB) atomicAdd(&S[b * DHP + 256 + tid], a1);
        }
        return;
    }
    // ---------------- xy: Lorentz similarity via bf16 MFMA, upper triangle
    {
        const int t_ = id - 1024;
        const int b = t_ >> 8;
        const int bx = t_ & 15, by = (t_ >> 4) & 15;
        if (bx < by) return;
        const int nb = seq[b];
        const int row0 = by * 128, col0 = bx * 128;
        if (row0 >= nb || col0 >= nb) return;
        const int wave = tid >> 6, lane = tid & 63;
        const int r0 = row0 + (wave >> 1) * 64, c0 = col0 + (wave & 1) * 64;
        if (c0 + 63 < r0 || r0 >= nb || c0 >= nb) return;   // wave-uniform exits
        const unsigned short* base = pxb + (size_t)b * TT * DHP;
        const int q = lane >> 4, m = lane & 15;
        f32x4 acc[4][4];
#pragma unroll
        for (int a = 0; a < 4; ++a)
#pragma unroll
            for (int c = 0; c < 4; ++c) acc[a][c] = (f32x4){0.f, 0.f, 0.f, 0.f};
        bf16x8 af0[4], bf0[4], af1[4], bf1[4];
        XLOAD(0, 0)
        int k0 = 0;
        for (; k0 + 64 <= DHP; k0 += 64) {
            XLOAD(1, k0 + 32)
            XMFMA(0)
            if (k0 + 64 < DHP) { XLOAD(0, k0 + 64) }
            XMFMA(1)
        }
        if (k0 < DHP) { XMFMA(0) }
        const float* b32 = px + (size_t)b * TT * DHP;
        float cj[4], ci[4][4];
#pragma unroll
        for (int nj = 0; nj < 4; ++nj) cj[nj] = b32[(size_t)(c0 + nj*16 + m) * DHP];
#pragma unroll
        for (int mi = 0; mi < 4; ++mi)
#pragma unroll
            for (int t = 0; t < 4; ++t) ci[mi][t] = b32[(size_t)(r0 + mi*16 + q*4 + t) * DHP];
#pragma unroll
        for (int mi = 0; mi < 4; ++mi)
#pragma unroll
            for (int nj = 0; nj < 4; ++nj)
#pragma unroll
                for (int t = 0; t < 4; ++t) {
                    int i = r0 + mi*16 + q*4 + t;
                    int j = c0 + nj*16 + m;
                    if (i < j && j < nb) {
                        float xyv = 2.f * ci[mi][t] * cj[nj] - acc[mi][nj][t];
                        float xym = fmaxf(xyv, 1.0f);
                        // xym >= 1.026 => x2 <= 0.798 < 0.8: no correction
                        if (xym < 1.026f) {
                            float dd = logf(xym + sqrtf(xym * xym - 1.0f + 1e-7f));
                            dd = fminf(fmaxf(dd, 1e-6f), 200.0f);
                            float x2v = expf(-dd);
                            if (x2v > 0.8f) {
                                float w = expf(x2v) - 1.0f;
                                atomicAdd(&den[b * TT + i], w);
                                atomicAdd(&den[b * TT + j], w);
                                const float* pi = b32 + (size_t)i * DHP;
                                const float* pj = b32 + (size_t)j * DHP;
                                float* ai = accb + ((size_t)(b * TT + i)) * DHP;
                                float* aj = accb + ((size_t)(b * TT + j)) * DHP;
                                for (int d = 0; d < DHP; ++d) {
                                    atomicAdd(&ai[d], w * pj[d]);
                                    atomicAdd(&aj[d], w * pi[d]);
                                }
                            }
                        }
                    }
                }
    }
}

// ------------------------------------------------- expmap0 (px fp32 + bf16)
// WAVE-PER-ROW (R10 win): 4 rows per 256-thr block, shfl_xor butterfly, no
// barriers, redundant per-lane cosh/sinh. Also zeroes this row's accb slice.
__global__ __launch_bounds__(256) void k_proj(
    const float* __restrict__ C2, const float* __restrict__ inputs,
    float* __restrict__ px, unsigned short* __restrict__ pxb,
    float* __restrict__ accb)
{
    const int r = blockIdx.x * 4 + (threadIdx.x >> 6);
    const int l = threadIdx.x & 63;
    float v[4];
#pragma unroll
    for (int e = 0; e < 2; ++e)              // dims 0..127 from C2
        v[e] = C2[(size_t)r * 128 + l + 64*e];
#pragma unroll
    for (int e = 2; e < 4; ++e)              // dims 128..255 from inputs tail
        v[e] = inputs[(size_t)r * 1152 + 1024 + (l + 64*e - 128)];
    float sq = v[0]*v[0] + v[1]*v[1] + v[2]*v[2] + v[3]*v[3];
#pragma unroll
    for (int o = 32; o > 0; o >>= 1) sq += __shfl_xor(sq, o, 64);
    float n2 = fmaxf(sq, 1e-12f);
    float n = sqrtf(n2);
    float cs0 = coshf(n);
    float cs1 = sinhf(n) / n;
    const size_t base = (size_t)r * DHP;
#pragma unroll
    for (int e = 0; e < 4; ++e) {
        int idx = l + 64*e;
        float sv = cs1 * v[e];
        px[base + 1 + idx] = sv;
        pxb[base + 1 + idx] = f2bf(sv);
        accb[base + idx] = 0.f;
    }
    if (l == 0) { px[base] = cs0; pxb[base] = f2bf(cs0); }
    if (l < DHP - DH_) { px[base + DH_ + l] = 0.f; pxb[base + DH_ + l] = 0; }
    if (l < 32) accb[base + 256 + l] = 0.f;
}

// ------------------------------------------------- Y1 = (S + corr + wd*px)/den
__global__ void k_y1(const float* __restrict__ accb, const float* __restrict__ S,
                     const float* __restrict__ den, const int* __restrict__ seq,
                     const float* __restrict__ px,
                     unsigned short* __restrict__ yh, unsigned short* __restrict__ yl)
{
    size_t idx = (size_t)blockIdx.x * 256 + threadIdx.x;
    if (idx >= NPX) return;
    int r = (int)(idx / DHP);
    int b = r >> 11, i = r & (TT - 1);
    int d = (int)(idx - (size_t)r * DHP);
    float out = 0.f;
    if (i < seq[b])
        out = (S[b * DHP + d] + accb[idx] + diag_w() * px[idx]) / den[r];
    unsigned short hh = f2bf(out);
    yh[idx] = hh;
    yl[idx] = f2bf(out - bf2f(hh));
}

// ------------------------------------------------- frame_prob
__global__ __launch_bounds__(256) void k_frame(
    const float* __restrict__ x1, const float* __restrict__ x2f,
    const float* __restrict__ cls_w, const float* __restrict__ cls_b,
    float* __restrict__ dout)
{
    const int r = blockIdx.x * 4 + (threadIdx.x >> 6);
    const int lane = threadIdx.x & 63;
    float s = 0.f;
#pragma unroll
    for (int t = 0; t < 2; ++t) {
        int g = lane + t * 64;
        float cw1 = cls_w[g];
        if (g == 0) cw1 = -cw1;      // signs: only dim 0 negated
        s += x1[(size_t)r * DG_ + g] * cw1;
        s += x2f[(size_t)r * DG_ + g] * cls_w[DG_ + g];
    }
#pragma unroll
    for (int o = 32; o > 0; o >>= 1) s += __shfl_down(s, o, 64);
    if (lane == 0) dout[8 + r] = 2.0f + 2.0f * s + cls_b[0];
}

// ------------------------------------------------- top-k MIL via radix select
// (R10 win: 4-pass MSD radix select replaces 66-barrier bitonic sort)
__global__ __launch_bounds__(1024) void k_clas(
    const int* __restrict__ seq, float* __restrict__ dout)
{
    __shared__ unsigned su[TT];
    __shared__ unsigned hist[256];
    __shared__ unsigned sh_prefix;
    __shared__ int sh_rem;
    __shared__ float wred[16];
    __shared__ int wcnt[16];
    const int b = blockIdx.x, tid = threadIdx.x;
    const int nb = seq[b];
    const int kk = nb / 16 + 1;
    // load + order-preserving transform (f>=0: bits|MSB; f<0: ~bits)
    for (int t = tid; t < TT; t += 1024) {
        unsigned u = 0u;   // invalid rows -> 0, below any valid transform
        if (t < nb) {
            unsigned x = __float_as_uint(dout[8 + b * TT + t]);
            u = (x & 0x80000000u) ? ~x : (x | 0x80000000u);
        }
        su[t] = u;
    }
    if (tid == 0) { sh_prefix = 0u; sh_rem = kk; }
    __syncthreads();
#pragma unroll
    for (int p = 0; p < 4; ++p) {
        const int shift = 24 - 8 * p;
        const unsigned hm = (p == 0) ? 0u : (0xFFFFFFFFu << (shift + 8));
        if (tid < 256) hist[tid] = 0u;
        __syncthreads();
        const unsigned pref = sh_prefix;
        for (int t = tid; t < TT; t += 1024) {
            unsigned u = su[t];
            if (u != 0u && (u & hm) == pref)
                atomicAdd(&hist[(u >> shift) & 0xFFu], 1u);
        }
        __syncthreads();
        if (tid == 0) {
            int rem = sh_rem;
            int v = 255;
            for (; v > 0; --v) {
                int c = (int)hist[v];
                if (c < rem) rem -= c;
                else break;
            }
            sh_rem = rem;
            sh_prefix = sh_prefix | ((unsigned)v << shift);
        }
        __syncthreads();
    }
    const unsigned T = sh_prefix;   // kk-th largest (transformed)
    float fsum = 0.f; int cnt = 0;
    for (int t = tid; t < TT; t += 1024) {
        unsigned u = su[t];
        if (u > T) {
            unsigned x = (u & 0x80000000u) ? (u ^ 0x80000000u) : ~u;
            fsum += __uint_as_float(x);
            ++cnt;
        }
    }
#pragma unroll
    for (int o = 32; o > 0; o >>= 1) {
        fsum += __shfl_down(fsum, o, 64);
        cnt  += __shfl_down(cnt, o, 64);
    }
    if ((tid & 63) == 0) { wred[tid >> 6] = fsum; wcnt[tid >> 6] = cnt; }
    __syncthreads();
    if (tid == 0) {
        float s = 0.f; int c = 0;
#pragma unroll
        for (int t = 0; t < 16; ++t) { s += wred[t]; c += wcnt[t]; }
        unsigned x = (T & 0x80000000u) ? (T ^ 0x80000000u) : ~T;
        s += (float)(kk - c) * __uint_as_float(x);   // tied-at-threshold share
        float mil = s / (float)kk;
        dout[b] = 1.f / (1.f + expf(-mil));
    }
}

// ---------------------------------------------------------------- launch
extern "C" void kernel_launch(void* const* d_in, const int* in_sizes, int n_in,
                              void* d_out, int out_size, void* d_ws, size_t ws_size,
                              hipStream_t stream) {
    (void)in_sizes; (void)n_in; (void)out_size; (void)ws_size;
    const float* inputs = (const float*)d_in[0];
    const int*   seq    = (const int*)d_in[1];
    const float* w1     = (const float*)d_in[2];
    const float* b1     = (const float*)d_in[3];
    const float* w2     = (const float*)d_in[4];
    const float* b2     = (const float*)d_in[5];
    const float* gw1    = (const float*)d_in[6];
    const float* gw2    = (const float*)d_in[7];
    const float* cls_w  = (const float*)d_in[8];
    const float* cls_b  = (const float*)d_in[9];
    float* dout = (float*)d_out;
    float* ws = (float*)d_ws;

    // o_big region: px + pxb + y2 + y1
    float* px  = ws + o_big;
    unsigned short* pxb = (unsigned short*)(ws + o_big + 4718592);
    unsigned short* y2h = (unsigned short*)(ws + o_big + 7077888);
    unsigned short* y2l = y2h + NPX;
    unsigned short* y1h = (unsigned short*)(ws + o_big + 11796480);
    unsigned short* y1l = y1h + NPX;
    // o_c1 region: C1h/C1l -> accb + x1
    unsigned short* C1h = (unsigned short*)(ws + o_c1);
    unsigned short* C1l = C1h + (size_t)MTOT * D1_;
    float* accb = ws + o_c1;
    float* x1   = ws + o_c1 + 4718592;
    // o_c2 region: C2 -> x2f
    float* C2  = ws + o_c2;
    float* x2f = ws + o_c2;
    // weights
    unsigned short* wsS = (unsigned short*)(ws + o_w);
    unsigned short *W1h = wsS + sw_w1h, *W1l = wsS + sw_w1l;
    unsigned short *W2h = wsS + sw_w2h, *W2l = wsS + sw_w2l;
    unsigned short *g1h = wsS + sw_g1h, *g1l = wsS + sw_g1l;
    unsigned short *g2h = wsS + sw_g2h, *g2l = wsS + sw_g2l;
    float* S   = ws + o_S;
    float* den = ws + o_den;

    // merged init + weight splits (1 dispatch)
    k_setup<<<928, 256, 0, stream>>>(den, seq, S, w1, w2, W1h, W1l, W2h, W2l,
                                     gw1, gw2, g1h, g1l, g2h, g2l);

    // MLP1: R3 best-measured config (512-thr, 128x128, BKC=32, B direct)
    gemm_mlp1<<<512, 512, 0, stream>>>(inputs, W1h, W1l, b1, C1h, C1l);
    // MLP2: 64-row tiles -> 256 blocks
    gemm_mlp2<<<256, 256, 0, stream>>>(C1h, C1l, W2h, W2l, b2, C2);

    // expmap0: wave-per-row + accb zeroing
    k_proj<<<MTOT / 4, 256, 0, stream>>>(C2, inputs, px, pxb, accb);

    // merged mid-phase: band(512) + ssum(512) + xy(2048) in ONE dispatch
    k_mid<<<3072, 256, 0, stream>>>(pxb, px, seq, den, accb, S, y2h, y2l);

    // Y1 = (S + corr + diag)/den -> split bf16
    k_y1<<<(int)(NPX / 256), 256, 0, stream>>>(accb, S, den, seq, px, y1h, y1l);

    // merged graph-conv projections via MFMA: 128-row tiles (best-measured)
    gemm_gc<<<dim3(1, MTOT / 128, 2), 256, 0, stream>>>(
        y1h, y1l, y2h, y2l, g1h, g1l, g2h, g2l, x1, x2f);

    // frame_prob + MIL (radix top-k select)
    k_frame<<<MTOT / 4, 256, 0, stream>>>(x1, x2f, cls_w, cls_b, dout);
    k_clas<<<BB, 1024, 0, stream>>>(seq, dout);
}